// Round 1
// baseline (2334.604 us; speedup 1.0000x reference)
//
#include <hip/hip_runtime.h>
#include <math.h>

#define Bv   32
#define Tv   12
#define Nv   512
#define DINv 3
#define DEv  16
#define HIDv 64
#define INXv 67   // DIN + HID
#define CSv  2
#define OUTv 12

__device__ __forceinline__ float sigmoidf_(float x) { return 1.0f / (1.0f + __expf(-x)); }

// ---------------------------------------------------------------------------
// W[g][n][k][i][o] = sum_d node_emb[n][d] * wp[g][d][k][i][o]
// grid (Nv, 3), block 256
__global__ __launch_bounds__(256) void k_wpre(const float* __restrict__ node_emb,
                                              const float* __restrict__ wp,
                                              float* __restrict__ W) {
  const int g = blockIdx.y;
  const int n = blockIdx.x;
  __shared__ float ne[DEv];
  if (threadIdx.x < DEv) ne[threadIdx.x] = node_emb[n * DEv + threadIdx.x];
  __syncthreads();
  const float* wpg = wp + (size_t)g * (DEv * 2 * INXv * HIDv);
  float* Wo = W + ((size_t)g * Nv + n) * (2 * INXv * HIDv);
  for (int j = threadIdx.x; j < 2 * INXv * HIDv; j += 256) {
    float s = 0.f;
#pragma unroll
    for (int d = 0; d < DEv; ++d) s += ne[d] * wpg[(size_t)d * (2 * INXv * HIDv) + j];
    Wo[j] = s;
  }
}

// TB[g][b][t][o] = sum_d time_emb[b][t][d] * bp[g][d][o]
// grid (Bv*Tv, 3), block 64
__global__ __launch_bounds__(64) void k_tb(const float* __restrict__ te,
                                           const float* __restrict__ bp,
                                           float* __restrict__ TB) {
  const int g = blockIdx.y;
  const int bt = blockIdx.x;
  const int b = bt / Tv, t = bt % Tv;
  const int o = threadIdx.x;
  float s = 0.f;
#pragma unroll
  for (int d = 0; d < DEv; ++d) s += te[(b * Tv + t) * DEv + d] * bp[(g * DEv + d) * HIDv + o];
  TB[(((size_t)g * Bv + b) * Tv + t) * HIDv + o] = s;
}

// ---------------------------------------------------------------------------
// Graph attention: xg2[buf][b][n][c] ; cols 0..63 = (s2 @ state-part),
// cols 64..66 = (s2 @ x-part).  V = [state | x].
// grid (Nv/64, Bv, ngates), block 256
__global__ __launch_bounds__(256) void k_gatt(const float* __restrict__ x,
                                              const float* __restrict__ node_emb,
                                              const float* __restrict__ te,
                                              const float* __restrict__ lng,
                                              const float* __restrict__ lnb,
                                              const float* __restrict__ src,   // B,N,HID (state or z*state)
                                              float* __restrict__ xg2,
                                              int t, int g0) {
  const int g = g0 + blockIdx.z;
  const int b = blockIdx.y;
  const int n0 = blockIdx.x * 64;
  __shared__ float qs[64][16];
  __shared__ float ks[64][16];
  __shared__ float vs[64][72];   // 0..63 state, 64..66 x, 67 zero-pad
  __shared__ float ps[64][65];
  const int tid = threadIdx.x;
  const int row = tid >> 2, q = tid & 3;

  // stage Q rows: emb = LN(node_emb + te) with gate-g params
  if (tid < 64) {
    float v[16]; float mu = 0.f;
#pragma unroll
    for (int d = 0; d < 16; ++d) { v[d] = node_emb[(n0 + tid) * 16 + d] + te[(b * Tv + t) * 16 + d]; mu += v[d]; }
    mu *= 0.0625f;
    float var = 0.f;
#pragma unroll
    for (int d = 0; d < 16; ++d) { float c = v[d] - mu; var += c * c; }
    var *= 0.0625f;
    const float rs = rsqrtf(var + 1e-12f);
#pragma unroll
    for (int d = 0; d < 16; ++d) qs[tid][d] = (v[d] - mu) * rs * lng[g * 16 + d] + lnb[g * 16 + d];
  }
  __syncthreads();
  float qreg[16];
#pragma unroll
  for (int d = 0; d < 16; ++d) qreg[d] = qs[row][d];

  float acc[16];
#pragma unroll
  for (int j = 0; j < 16; ++j) acc[j] = 0.f;
  float accx = 0.f, mrow = -1e30f, den = 0.f;

  for (int m0 = 0; m0 < Nv; m0 += 64) {
    __syncthreads();   // protect ks/vs/ps reuse across tiles
    if (tid < 64) {
      float v[16]; float mu = 0.f;
#pragma unroll
      for (int d = 0; d < 16; ++d) { v[d] = node_emb[(m0 + tid) * 16 + d] + te[(b * Tv + t) * 16 + d]; mu += v[d]; }
      mu *= 0.0625f;
      float var = 0.f;
#pragma unroll
      for (int d = 0; d < 16; ++d) { float c = v[d] - mu; var += c * c; }
      var *= 0.0625f;
      const float rs = rsqrtf(var + 1e-12f);
#pragma unroll
      for (int d = 0; d < 16; ++d) ks[tid][d] = (v[d] - mu) * rs * lng[g * 16 + d] + lnb[g * 16 + d];
    }
#pragma unroll
    for (int it = 0; it < 4; ++it) {
      const int idx = tid + it * 256;
      const int m = idx >> 4, c4 = idx & 15;
      const float4 sv = *(const float4*)&src[((size_t)b * Nv + (m0 + m)) * HIDv + c4 * 4];
      *(float4*)&vs[m][c4 * 4] = sv;
    }
    if (tid < 64) {
      const float* xp = &x[(((size_t)b * Tv + t) * Nv + (m0 + tid)) * DINv];
      vs[tid][64] = xp[0]; vs[tid][65] = xp[1]; vs[tid][66] = xp[2]; vs[tid][67] = 0.f;
    }
    __syncthreads();

    float s[16];
#pragma unroll
    for (int i = 0; i < 16; ++i) {
      const int m = q * 16 + i;
      float a = 0.f;
#pragma unroll
      for (int d = 0; d < 16; ++d) a += qreg[d] * ks[m][d];
      s[i] = a;
    }
    float tmax = s[0];
#pragma unroll
    for (int i = 1; i < 16; ++i) tmax = fmaxf(tmax, s[i]);
    tmax = fmaxf(tmax, __shfl_xor(tmax, 1));
    tmax = fmaxf(tmax, __shfl_xor(tmax, 2));
    const float mnew = fmaxf(mrow, tmax);
    const float fac = __expf(mrow - mnew);
    mrow = mnew;
    den *= fac; accx *= fac;
#pragma unroll
    for (int j = 0; j < 16; ++j) acc[j] *= fac;
    float psum = 0.f;
#pragma unroll
    for (int i = 0; i < 16; ++i) {
      const float p = __expf(s[i] - mnew);
      ps[row][q * 16 + i] = p;
      psum += p;
    }
    den += psum;
    __syncthreads();   // ps visible to whole quad-row

#pragma unroll 4
    for (int m = 0; m < 64; ++m) {
      const float pm = ps[row][m];
#pragma unroll
      for (int j4 = 0; j4 < 4; ++j4) {
        const float4 v4 = *(const float4*)&vs[m][q * 16 + j4 * 4];
        acc[j4 * 4 + 0] += pm * v4.x;
        acc[j4 * 4 + 1] += pm * v4.y;
        acc[j4 * 4 + 2] += pm * v4.z;
        acc[j4 * 4 + 3] += pm * v4.w;
      }
      accx += pm * vs[m][64 + q];   // q==3 hits the zero pad column
    }
  }
  den += __shfl_xor(den, 1);
  den += __shfl_xor(den, 2);
  const float rden = 1.f / den;
  float* outp = xg2 + (((size_t)blockIdx.z * Bv + b) * Nv + (n0 + row)) * 72;
#pragma unroll
  for (int j4 = 0; j4 < 4; ++j4) {
    float4 o4;
    o4.x = acc[j4 * 4 + 0] * rden; o4.y = acc[j4 * 4 + 1] * rden;
    o4.z = acc[j4 * 4 + 2] * rden; o4.w = acc[j4 * 4 + 3] * rden;
    *(float4*)&outp[q * 16 + j4 * 4] = o4;
  }
  if (q < 3) outp[64 + q] = accx * rden;
}

// ---------------------------------------------------------------------------
// K2: gout = xt@W0[n] + xg2@W1[n] + tb ; q=LN(gout); temporal attention over
// states[0..t]; pre = gout + o; gate nonlinearity (+GRU update for g==2).
// grid (Nv, 1, ngates), block 256
__global__ __launch_bounds__(256) void k_k2(const float* __restrict__ x,
                                            const float* __restrict__ Wb,
                                            const float* __restrict__ TB,
                                            const float* __restrict__ oln_g,
                                            const float* __restrict__ oln_b,
                                            const float* __restrict__ xg2,
                                            const float* __restrict__ srcst,  // state (g<2) or z*state (g==2)
                                            const float* __restrict__ states, // base, [k][b][n][o]
                                            const float* __restrict__ stcur,  // states[t]
                                            float* __restrict__ zs,
                                            float* __restrict__ rb,
                                            float* __restrict__ hnew,         // states[t+1]
                                            int t, int g0) {
  const int zb = blockIdx.z;
  const int g = g0 + zb;
  const int n = blockIdx.x;
  __shared__ float Ws[2 * INXv * HIDv];   // [k][i][o]
  __shared__ float xts[INXv][34];
  __shared__ float g2s[INXv][34];
  const int tid = threadIdx.x;

  const float* Wp = Wb + ((size_t)g * Nv + n) * (2 * INXv * HIDv);
  for (int j = tid; j < (2 * INXv * HIDv) / 4; j += 256)
    ((float4*)Ws)[j] = ((const float4*)Wp)[j];
  {
    const int b = tid >> 3, cc = tid & 7;
    const float* sp = &srcst[((size_t)b * Nv + n) * HIDv + cc * 8];
    const float4 a = *(const float4*)sp;
    const float4 c = *(const float4*)(sp + 4);
    xts[3 + cc * 8 + 0][b] = a.x; xts[3 + cc * 8 + 1][b] = a.y;
    xts[3 + cc * 8 + 2][b] = a.z; xts[3 + cc * 8 + 3][b] = a.w;
    xts[3 + cc * 8 + 4][b] = c.x; xts[3 + cc * 8 + 5][b] = c.y;
    xts[3 + cc * 8 + 6][b] = c.z; xts[3 + cc * 8 + 7][b] = c.w;
    const float* gp = &xg2[(((size_t)zb * Bv + b) * Nv + n) * 72 + cc * 8];
    const float4 p = *(const float4*)gp;
    const float4 r2 = *(const float4*)(gp + 4);
    g2s[3 + cc * 8 + 0][b] = p.x;  g2s[3 + cc * 8 + 1][b] = p.y;
    g2s[3 + cc * 8 + 2][b] = p.z;  g2s[3 + cc * 8 + 3][b] = p.w;
    g2s[3 + cc * 8 + 4][b] = r2.x; g2s[3 + cc * 8 + 5][b] = r2.y;
    g2s[3 + cc * 8 + 6][b] = r2.z; g2s[3 + cc * 8 + 7][b] = r2.w;
  }
  if (tid < Bv) {
    const int b = tid;
    const float* xp = &x[(((size_t)b * Tv + t) * Nv + n) * DINv];
    xts[0][b] = xp[0]; xts[1][b] = xp[1]; xts[2][b] = xp[2];
    const float* gp = &xg2[(((size_t)zb * Bv + b) * Nv + n) * 72 + 64];
    g2s[0][b] = gp[0]; g2s[1][b] = gp[1]; g2s[2][b] = gp[2];
  }
  __syncthreads();

  const int og = tid & 15, bp = tid >> 4;
  const int b0 = bp * 2, b1 = b0 + 1;
  float a0[4] = {0, 0, 0, 0}, a1[4] = {0, 0, 0, 0};
  for (int i = 0; i < INXv; ++i) {
    const float xa = xts[i][b0], xb = xts[i][b1];
    const float ga = g2s[i][b0], gb = g2s[i][b1];
    const float4 w0 = *(const float4*)&Ws[i * HIDv + og * 4];
    const float4 w1 = *(const float4*)&Ws[INXv * HIDv + i * HIDv + og * 4];
    a0[0] += xa * w0.x + ga * w1.x; a0[1] += xa * w0.y + ga * w1.y;
    a0[2] += xa * w0.z + ga * w1.z; a0[3] += xa * w0.w + ga * w1.w;
    a1[0] += xb * w0.x + gb * w1.x; a1[1] += xb * w0.y + gb * w1.y;
    a1[2] += xb * w0.z + gb * w1.z; a1[3] += xb * w0.w + gb * w1.w;
  }
  {
    const float* t0 = TB + (((size_t)g * Bv + b0) * Tv + t) * HIDv + og * 4;
    const float* t1 = TB + (((size_t)g * Bv + b1) * Tv + t) * HIDv + og * 4;
#pragma unroll
    for (int j = 0; j < 4; ++j) { a0[j] += t0[j]; a1[j] += t1[j]; }
  }
  // LN over 64 (shfl across og = low 4 lane bits)
  float s0 = a0[0] + a0[1] + a0[2] + a0[3];
  float s1 = a1[0] + a1[1] + a1[2] + a1[3];
#pragma unroll
  for (int msk = 1; msk < 16; msk <<= 1) { s0 += __shfl_xor(s0, msk); s1 += __shfl_xor(s1, msk); }
  const float mu0 = s0 * (1.f / 64.f), mu1 = s1 * (1.f / 64.f);
  float v0 = 0.f, v1 = 0.f;
#pragma unroll
  for (int j = 0; j < 4; ++j) { const float c0 = a0[j] - mu0, c1 = a1[j] - mu1; v0 += c0 * c0; v1 += c1 * c1; }
#pragma unroll
  for (int msk = 1; msk < 16; msk <<= 1) { v0 += __shfl_xor(v0, msk); v1 += __shfl_xor(v1, msk); }
  const float rs0 = rsqrtf(v0 * (1.f / 64.f) + 1e-5f);
  const float rs1 = rsqrtf(v1 * (1.f / 64.f) + 1e-5f);
  float q0[4], q1[4];
#pragma unroll
  for (int j = 0; j < 4; ++j) {
    const float gg = oln_g[g * HIDv + og * 4 + j], bb = oln_b[g * HIDv + og * 4 + j];
    q0[j] = (a0[j] - mu0) * rs0 * gg + bb;
    q1[j] = (a1[j] - mu1) * rs1 * gg + bb;
  }
  // temporal attention over k=0..t (head = og>>2, shfl over og&3)
  float m0r = -1e30f, m1r = -1e30f, d0 = 0.f, d1 = 0.f;
  float o0[4] = {0, 0, 0, 0}, o1[4] = {0, 0, 0, 0};
  for (int k = 0; k <= t; ++k) {
    const float4 kv0 = *(const float4*)&states[(((size_t)k * Bv + b0) * Nv + n) * HIDv + og * 4];
    const float4 kv1 = *(const float4*)&states[(((size_t)k * Bv + b1) * Nv + n) * HIDv + og * 4];
    float sc0 = q0[0] * kv0.x + q0[1] * kv0.y + q0[2] * kv0.z + q0[3] * kv0.w;
    float sc1 = q1[0] * kv1.x + q1[1] * kv1.y + q1[2] * kv1.z + q1[3] * kv1.w;
    sc0 += __shfl_xor(sc0, 1); sc0 += __shfl_xor(sc0, 2);
    sc1 += __shfl_xor(sc1, 1); sc1 += __shfl_xor(sc1, 2);
    sc0 *= 0.25f; sc1 *= 0.25f;   // / sqrt(hd=16)
    const float mn0 = fmaxf(m0r, sc0), mn1 = fmaxf(m1r, sc1);
    const float f0 = __expf(m0r - mn0), f1 = __expf(m1r - mn1);
    const float p0 = __expf(sc0 - mn0), p1 = __expf(sc1 - mn1);
    m0r = mn0; m1r = mn1;
    d0 = d0 * f0 + p0; d1 = d1 * f1 + p1;
    o0[0] = o0[0] * f0 + p0 * kv0.x; o0[1] = o0[1] * f0 + p0 * kv0.y;
    o0[2] = o0[2] * f0 + p0 * kv0.z; o0[3] = o0[3] * f0 + p0 * kv0.w;
    o1[0] = o1[0] * f1 + p1 * kv1.x; o1[1] = o1[1] * f1 + p1 * kv1.y;
    o1[2] = o1[2] * f1 + p1 * kv1.z; o1[3] = o1[3] * f1 + p1 * kv1.w;
  }
  const float ro0 = 1.f / d0, ro1 = 1.f / d1;
  float pre0[4], pre1[4];
#pragma unroll
  for (int j = 0; j < 4; ++j) { pre0[j] = a0[j] + o0[j] * ro0; pre1[j] = a1[j] + o1[j] * ro1; }

  const size_t off0 = ((size_t)b0 * Nv + n) * HIDv + og * 4;
  const size_t off1 = ((size_t)b1 * Nv + n) * HIDv + og * 4;
  if (g == 0) {
    const float4 st0 = *(const float4*)&stcur[off0];
    const float4 st1 = *(const float4*)&stcur[off1];
    float4 w0, w1;
    w0.x = sigmoidf_(pre0[0]) * st0.x; w0.y = sigmoidf_(pre0[1]) * st0.y;
    w0.z = sigmoidf_(pre0[2]) * st0.z; w0.w = sigmoidf_(pre0[3]) * st0.w;
    w1.x = sigmoidf_(pre1[0]) * st1.x; w1.y = sigmoidf_(pre1[1]) * st1.y;
    w1.z = sigmoidf_(pre1[2]) * st1.z; w1.w = sigmoidf_(pre1[3]) * st1.w;
    *(float4*)&zs[off0] = w0; *(float4*)&zs[off1] = w1;
  } else if (g == 1) {
    float4 w0, w1;
    w0.x = sigmoidf_(pre0[0]); w0.y = sigmoidf_(pre0[1]);
    w0.z = sigmoidf_(pre0[2]); w0.w = sigmoidf_(pre0[3]);
    w1.x = sigmoidf_(pre1[0]); w1.y = sigmoidf_(pre1[1]);
    w1.z = sigmoidf_(pre1[2]); w1.w = sigmoidf_(pre1[3]);
    *(float4*)&rb[off0] = w0; *(float4*)&rb[off1] = w1;
  } else {
    const float4 st0 = *(const float4*)&stcur[off0];
    const float4 st1 = *(const float4*)&stcur[off1];
    const float4 r0 = *(const float4*)&rb[off0];
    const float4 r1 = *(const float4*)&rb[off1];
    float4 w0, w1;
    w0.x = r0.x * st0.x + (1.f - r0.x) * tanhf(pre0[0]);
    w0.y = r0.y * st0.y + (1.f - r0.y) * tanhf(pre0[1]);
    w0.z = r0.z * st0.z + (1.f - r0.z) * tanhf(pre0[2]);
    w0.w = r0.w * st0.w + (1.f - r0.w) * tanhf(pre0[3]);
    w1.x = r1.x * st1.x + (1.f - r1.x) * tanhf(pre1[0]);
    w1.y = r1.y * st1.y + (1.f - r1.y) * tanhf(pre1[1]);
    w1.z = r1.z * st1.z + (1.f - r1.z) * tanhf(pre1[2]);
    w1.w = r1.w * st1.w + (1.f - r1.w) * tanhf(pre1[3]);
    *(float4*)&hnew[off0] = w0; *(float4*)&hnew[off1] = w1;
  }
}

// ---------------------------------------------------------------------------
// pred[b][o][n] = sum_c sum_h states[11+c][b][n][h]*pw[o][c][h] + pb[o]
// grid (Nv/256, Bv), block 256
__global__ __launch_bounds__(256) void k_pred(const float* __restrict__ states,
                                              const float* __restrict__ pw,
                                              const float* __restrict__ pb,
                                              float* __restrict__ out) {
  __shared__ float pws[OUTv * CSv * HIDv];
  __shared__ float pbs[OUTv];
  const int tid = threadIdx.x;
  for (int j = tid; j < OUTv * CSv * HIDv; j += 256) pws[j] = pw[j];
  if (tid < OUTv) pbs[tid] = pb[tid];
  __syncthreads();
  const int n = blockIdx.x * 256 + tid;
  const int b = blockIdx.y;
  const float* s0p = &states[(((size_t)(Tv - 1) * Bv + b) * Nv + n) * HIDv];
  const float* s1p = &states[(((size_t)Tv * Bv + b) * Nv + n) * HIDv];
  float4 va[16], vb[16];
#pragma unroll
  for (int j = 0; j < 16; ++j) {
    va[j] = *(const float4*)&s0p[j * 4];
    vb[j] = *(const float4*)&s1p[j * 4];
  }
#pragma unroll
  for (int o = 0; o < OUTv; ++o) {
    float acc = pbs[o];
    const float* w0 = &pws[(o * CSv + 0) * HIDv];
    const float* w1 = &pws[(o * CSv + 1) * HIDv];
#pragma unroll
    for (int j = 0; j < 16; ++j) {
      acc += va[j].x * w0[j * 4 + 0] + va[j].y * w0[j * 4 + 1] +
             va[j].z * w0[j * 4 + 2] + va[j].w * w0[j * 4 + 3];
      acc += vb[j].x * w1[j * 4 + 0] + vb[j].y * w1[j * 4 + 1] +
             vb[j].z * w1[j * 4 + 2] + vb[j].w * w1[j * 4 + 3];
    }
    out[((size_t)b * OUTv + o) * Nv + n] = acc;
  }
}

// ---------------------------------------------------------------------------
extern "C" void kernel_launch(void* const* d_in, const int* in_sizes, int n_in,
                              void* d_out, int out_size, void* d_ws, size_t ws_size,
                              hipStream_t stream) {
  (void)in_sizes; (void)n_in; (void)out_size; (void)ws_size;
  const float* x        = (const float*)d_in[0];
  const float* node_emb = (const float*)d_in[1];
  const float* time_emb = (const float*)d_in[2];
  const float* wp       = (const float*)d_in[3];
  const float* bp       = (const float*)d_in[4];
  const float* gcn_g    = (const float*)d_in[5];
  const float* gcn_b    = (const float*)d_in[6];
  const float* out_g    = (const float*)d_in[7];
  const float* out_b    = (const float*)d_in[8];
  const float* pred_w   = (const float*)d_in[9];
  const float* pred_b   = (const float*)d_in[10];

  float* ws = (float*)d_ws;
  float* W   = ws;                                            // 3*512*2*67*64 = 13172736
  float* TB  = W  + (size_t)3 * Nv * 2 * INXv * HIDv;         // 73728
  float* ST  = TB + (size_t)3 * Bv * Tv * HIDv;               // 13*32*512*64 = 13631488
  float* XG  = ST + (size_t)(Tv + 1) * Bv * Nv * HIDv;        // 2*32*512*72 = 2359296
  float* ZS  = XG + (size_t)2 * Bv * Nv * 72;                 // 1048576
  float* RB  = ZS + (size_t)Bv * Nv * HIDv;                   // 1048576

  // h0 = 0
  hipMemsetAsync(ST, 0, (size_t)Bv * Nv * HIDv * sizeof(float), stream);
  k_wpre<<<dim3(Nv, 3), 256, 0, stream>>>(node_emb, wp, W);
  k_tb<<<dim3(Bv * Tv, 3), 64, 0, stream>>>(time_emb, bp, TB);

  for (int t = 0; t < Tv; ++t) {
    float* st_t  = ST + (size_t)t * Bv * Nv * HIDv;
    float* st_t1 = st_t + (size_t)Bv * Nv * HIDv;
    // phase A: g=0 (z) and g=1 (r)
    k_gatt<<<dim3(Nv / 64, Bv, 2), 256, 0, stream>>>(x, node_emb, time_emb, gcn_g, gcn_b,
                                                     st_t, XG, t, 0);
    k_k2<<<dim3(Nv, 1, 2), 256, 0, stream>>>(x, W, TB, out_g, out_b, XG,
                                             st_t, ST, st_t, ZS, RB, st_t1, t, 0);
    // phase B: g=2 (candidate) + GRU update
    k_gatt<<<dim3(Nv / 64, Bv, 1), 256, 0, stream>>>(x, node_emb, time_emb, gcn_g, gcn_b,
                                                     ZS, XG, t, 2);
    k_k2<<<dim3(Nv, 1, 1), 256, 0, stream>>>(x, W, TB, out_g, out_b, XG,
                                             ZS, ST, st_t, ZS, RB, st_t1, t, 2);
  }
  k_pred<<<dim3(Nv / 256, Bv), 256, 0, stream>>>(ST, pred_w, pred_b, (float*)d_out);
}

// Round 2
// 2120.320 us; speedup vs baseline: 1.1011x; 1.1011x over previous
//
#include <hip/hip_runtime.h>
#include <math.h>

#define Bv   32
#define Tv   12
#define Nv   512
#define DINv 3
#define DEv  16
#define HIDv 64
#define INXv 67   // DIN + HID
#define CSv  2
#define OUTv 12

__device__ __forceinline__ float sigmoidf_(float x) { return 1.0f / (1.0f + __expf(-x)); }

// ---------------------------------------------------------------------------
// embAll[g][t][b][n][d] = LN(node_emb[n] + time_emb[b,t]) with gate-g params
// grid (Nv/128, Tv, Bv), block 384 (3 gates x 128 nodes)
__global__ __launch_bounds__(384) void k_emb(const float* __restrict__ node_emb,
                                             const float* __restrict__ te,
                                             const float* __restrict__ lng,
                                             const float* __restrict__ lnb,
                                             float* __restrict__ embAll) {
  const int t = blockIdx.y, b = blockIdx.z;
  const int g = threadIdx.x >> 7;          // 0..2
  const int nl = threadIdx.x & 127;
  const int n = blockIdx.x * 128 + nl;
  float v[16];
  float mu = 0.f;
#pragma unroll
  for (int d = 0; d < 16; ++d) {
    v[d] = node_emb[n * 16 + d] + te[(b * Tv + t) * 16 + d];
    mu += v[d];
  }
  mu *= 0.0625f;
  float var = 0.f;
#pragma unroll
  for (int d = 0; d < 16; ++d) { const float c = v[d] - mu; var += c * c; }
  var *= 0.0625f;
  const float rs = rsqrtf(var + 1e-12f);
  float* op = embAll + ((((size_t)g * Tv + t) * Bv + b) * Nv + n) * 16;
#pragma unroll
  for (int d = 0; d < 16; ++d)
    op[d] = (v[d] - mu) * rs * lng[g * 16 + d] + lnb[g * 16 + d];
}

// ---------------------------------------------------------------------------
// W[g][n][k][i][o] = sum_d node_emb[n][d] * wp[g][d][k][i][o]
__global__ __launch_bounds__(256) void k_wpre(const float* __restrict__ node_emb,
                                              const float* __restrict__ wp,
                                              float* __restrict__ W) {
  const int g = blockIdx.y;
  const int n = blockIdx.x;
  __shared__ float ne[DEv];
  if (threadIdx.x < DEv) ne[threadIdx.x] = node_emb[n * DEv + threadIdx.x];
  __syncthreads();
  const float* wpg = wp + (size_t)g * (DEv * 2 * INXv * HIDv);
  float* Wo = W + ((size_t)g * Nv + n) * (2 * INXv * HIDv);
  for (int j = threadIdx.x; j < 2 * INXv * HIDv; j += 256) {
    float s = 0.f;
#pragma unroll
    for (int d = 0; d < DEv; ++d) s += ne[d] * wpg[(size_t)d * (2 * INXv * HIDv) + j];
    Wo[j] = s;
  }
}

// TB[g][b][t][o] = sum_d time_emb[b][t][d] * bp[g][d][o]
__global__ __launch_bounds__(64) void k_tb(const float* __restrict__ te,
                                           const float* __restrict__ bp,
                                           float* __restrict__ TB) {
  const int g = blockIdx.y;
  const int bt = blockIdx.x;
  const int b = bt / Tv, t = bt % Tv;
  const int o = threadIdx.x;
  float s = 0.f;
#pragma unroll
  for (int d = 0; d < DEv; ++d) s += te[(b * Tv + t) * DEv + d] * bp[(g * DEv + d) * HIDv + o];
  TB[(((size_t)g * Bv + b) * Tv + t) * HIDv + o] = s;
}

// ---------------------------------------------------------------------------
// Graph attention, 512 threads / 8 waves / 64 rows / 8 lanes per row.
// xg2[buf][b][n][c]: c 0..63 = s2 @ state-part, 64..66 = s2 @ x-part.
// grid (Nv/64, Bv, ngates)
__global__ __launch_bounds__(512, 4) void k_gatt(const float* __restrict__ x,
                                                 const float* __restrict__ embAll,
                                                 const float* __restrict__ src,  // B,N,HID
                                                 float* __restrict__ xg2,
                                                 int t, int g0) {
  const int g = g0 + blockIdx.z;
  const int b = blockIdx.y;
  const int n0 = blockIdx.x * 64;
  const int tid = threadIdx.x;
  const int row = tid >> 3, oct = tid & 7;
  __shared__ float ksT[16][68];   // K transposed, padded
  __shared__ float vs[64][76];    // state-part V tile
  __shared__ float ps[64][68];    // softmax numerators
  __shared__ float xls[3][68];    // x-part V tile (transposed)

  const float* embB = embAll + (((size_t)g * Tv + t) * Bv + b) * (size_t)(Nv * 16);
  const float* xb = x + (((size_t)b * Tv + t)) * (size_t)(Nv * DINv);

  // Q for this row (LN already applied in embAll); 8 lanes broadcast-read
  float q[16];
  {
    const float* qp = embB + (size_t)(n0 + row) * 16;
#pragma unroll
    for (int d4 = 0; d4 < 4; ++d4) {
      const float4 qv = *(const float4*)&qp[d4 * 4];
      q[d4 * 4 + 0] = qv.x; q[d4 * 4 + 1] = qv.y;
      q[d4 * 4 + 2] = qv.z; q[d4 * 4 + 3] = qv.w;
    }
  }

  float acc[8];
#pragma unroll
  for (int j = 0; j < 8; ++j) acc[j] = 0.f;
  float ax0 = 0.f, ax1 = 0.f, ax2 = 0.f;
  float mrow = -1e30f, den = 0.f;

  for (int m0 = 0; m0 < Nv; m0 += 64) {
    __syncthreads();
    // stage K tile transposed: 64x16 -> ksT[16][m]
    if (tid < 256) {
      const int mr = tid >> 2, d4 = tid & 3;
      const float4 kv = *(const float4*)&embB[(size_t)(m0 + mr) * 16 + d4 * 4];
      ksT[d4 * 4 + 0][mr] = kv.x; ksT[d4 * 4 + 1][mr] = kv.y;
      ksT[d4 * 4 + 2][mr] = kv.z; ksT[d4 * 4 + 3][mr] = kv.w;
    }
    // stage V (state) tile: 64x64
#pragma unroll
    for (int it = 0; it < 2; ++it) {
      const int idx = tid + it * 512;
      const int m = idx >> 4, c4 = idx & 15;
      *(float4*)&vs[m][c4 * 4] =
          *(const float4*)&src[((size_t)b * Nv + m0 + m) * HIDv + c4 * 4];
    }
    // stage x tile transposed: xls[c][m]
    if (tid < 192) xls[tid % 3][tid / 3] = xb[(size_t)m0 * 3 + tid];
    __syncthreads();

    // scores for this lane's 8 m values (m = oct*8+i)
    float s[8];
#pragma unroll
    for (int i = 0; i < 8; ++i) s[i] = 0.f;
#pragma unroll
    for (int d = 0; d < 16; ++d) {
      const float qd = q[d];
      const float4 k0 = *(const float4*)&ksT[d][oct * 8];
      const float4 k1 = *(const float4*)&ksT[d][oct * 8 + 4];
      s[0] += qd * k0.x; s[1] += qd * k0.y; s[2] += qd * k0.z; s[3] += qd * k0.w;
      s[4] += qd * k1.x; s[5] += qd * k1.y; s[6] += qd * k1.z; s[7] += qd * k1.w;
    }
    float tmax = s[0];
#pragma unroll
    for (int i = 1; i < 8; ++i) tmax = fmaxf(tmax, s[i]);
    tmax = fmaxf(tmax, __shfl_xor(tmax, 1));
    tmax = fmaxf(tmax, __shfl_xor(tmax, 2));
    tmax = fmaxf(tmax, __shfl_xor(tmax, 4));
    const float mnew = fmaxf(mrow, tmax);
    const float fac = __expf(mrow - mnew);
    mrow = mnew;
    float p[8], psum = 0.f;
#pragma unroll
    for (int i = 0; i < 8; ++i) { p[i] = __expf(s[i] - mnew); psum += p[i]; }
    den = den * fac + psum;
#pragma unroll
    for (int j = 0; j < 8; ++j) acc[j] *= fac;
    ax0 *= fac; ax1 *= fac; ax2 *= fac;
    *(float4*)&ps[row][oct * 8] = make_float4(p[0], p[1], p[2], p[3]);
    *(float4*)&ps[row][oct * 8 + 4] = make_float4(p[4], p[5], p[6], p[7]);
    // x-part with register p over this lane's own m's
#pragma unroll
    for (int i = 0; i < 8; ++i) {
      ax0 += p[i] * xls[0][oct * 8 + i];
      ax1 += p[i] * xls[1][oct * 8 + i];
      ax2 += p[i] * xls[2][oct * 8 + i];
    }
    __syncthreads();

    // PV: this lane accumulates cols [oct*8, oct*8+8) over all 64 m
#pragma unroll 4
    for (int mq = 0; mq < 16; ++mq) {
      const float4 pm = *(const float4*)&ps[row][mq * 4];
#pragma unroll
      for (int u = 0; u < 4; ++u) {
        const int m = mq * 4 + u;
        const float pmu = (u == 0) ? pm.x : (u == 1) ? pm.y : (u == 2) ? pm.z : pm.w;
        const float4 v0 = *(const float4*)&vs[m][oct * 8];
        const float4 v1 = *(const float4*)&vs[m][oct * 8 + 4];
        acc[0] += pmu * v0.x; acc[1] += pmu * v0.y;
        acc[2] += pmu * v0.z; acc[3] += pmu * v0.w;
        acc[4] += pmu * v1.x; acc[5] += pmu * v1.y;
        acc[6] += pmu * v1.z; acc[7] += pmu * v1.w;
      }
    }
  }
  // denominator: reduce over the 8 lanes of this row
  den += __shfl_xor(den, 1);
  den += __shfl_xor(den, 2);
  den += __shfl_xor(den, 4);
  const float rden = 1.f / den;
  float* outp = xg2 + (((size_t)blockIdx.z * Bv + b) * Nv + n0 + row) * 72;
  float4 o0, o1;
  o0.x = acc[0] * rden; o0.y = acc[1] * rden; o0.z = acc[2] * rden; o0.w = acc[3] * rden;
  o1.x = acc[4] * rden; o1.y = acc[5] * rden; o1.z = acc[6] * rden; o1.w = acc[7] * rden;
  *(float4*)&outp[oct * 8] = o0;
  *(float4*)&outp[oct * 8 + 4] = o1;
  ax0 += __shfl_xor(ax0, 1); ax0 += __shfl_xor(ax0, 2); ax0 += __shfl_xor(ax0, 4);
  ax1 += __shfl_xor(ax1, 1); ax1 += __shfl_xor(ax1, 2); ax1 += __shfl_xor(ax1, 4);
  ax2 += __shfl_xor(ax2, 1); ax2 += __shfl_xor(ax2, 2); ax2 += __shfl_xor(ax2, 4);
  if (oct == 0) { outp[64] = ax0 * rden; outp[65] = ax1 * rden; outp[66] = ax2 * rden; }
}

// ---------------------------------------------------------------------------
// K2: gout = xt@W0[n] + xg2@W1[n] + tb ; q=LN(gout); temporal attention over
// states[0..t]; pre = gout + o; gate nonlinearity (+GRU update for g==2).
// grid (Nv, 1, ngates), block 256
__global__ __launch_bounds__(256) void k_k2(const float* __restrict__ x,
                                            const float* __restrict__ Wb,
                                            const float* __restrict__ TB,
                                            const float* __restrict__ oln_g,
                                            const float* __restrict__ oln_b,
                                            const float* __restrict__ xg2,
                                            const float* __restrict__ srcst,
                                            const float* __restrict__ states,
                                            const float* __restrict__ stcur,
                                            float* __restrict__ zs,
                                            float* __restrict__ rb,
                                            float* __restrict__ hnew,
                                            int t, int g0) {
  const int zb = blockIdx.z;
  const int g = g0 + zb;
  const int n = blockIdx.x;
  __shared__ float Ws[2 * INXv * HIDv];
  __shared__ float xts[INXv][34];
  __shared__ float g2s[INXv][34];
  const int tid = threadIdx.x;

  const float* Wp = Wb + ((size_t)g * Nv + n) * (2 * INXv * HIDv);
  for (int j = tid; j < (2 * INXv * HIDv) / 4; j += 256)
    ((float4*)Ws)[j] = ((const float4*)Wp)[j];
  {
    const int b = tid >> 3, cc = tid & 7;
    const float* sp = &srcst[((size_t)b * Nv + n) * HIDv + cc * 8];
    const float4 a = *(const float4*)sp;
    const float4 c = *(const float4*)(sp + 4);
    xts[3 + cc * 8 + 0][b] = a.x; xts[3 + cc * 8 + 1][b] = a.y;
    xts[3 + cc * 8 + 2][b] = a.z; xts[3 + cc * 8 + 3][b] = a.w;
    xts[3 + cc * 8 + 4][b] = c.x; xts[3 + cc * 8 + 5][b] = c.y;
    xts[3 + cc * 8 + 6][b] = c.z; xts[3 + cc * 8 + 7][b] = c.w;
    const float* gp = &xg2[(((size_t)zb * Bv + b) * Nv + n) * 72 + cc * 8];
    const float4 p = *(const float4*)gp;
    const float4 r2 = *(const float4*)(gp + 4);
    g2s[3 + cc * 8 + 0][b] = p.x;  g2s[3 + cc * 8 + 1][b] = p.y;
    g2s[3 + cc * 8 + 2][b] = p.z;  g2s[3 + cc * 8 + 3][b] = p.w;
    g2s[3 + cc * 8 + 4][b] = r2.x; g2s[3 + cc * 8 + 5][b] = r2.y;
    g2s[3 + cc * 8 + 6][b] = r2.z; g2s[3 + cc * 8 + 7][b] = r2.w;
  }
  if (tid < Bv) {
    const int b = tid;
    const float* xp = &x[(((size_t)b * Tv + t) * Nv + n) * DINv];
    xts[0][b] = xp[0]; xts[1][b] = xp[1]; xts[2][b] = xp[2];
    const float* gp = &xg2[(((size_t)zb * Bv + b) * Nv + n) * 72 + 64];
    g2s[0][b] = gp[0]; g2s[1][b] = gp[1]; g2s[2][b] = gp[2];
  }
  __syncthreads();

  const int og = tid & 15, bp = tid >> 4;
  const int b0 = bp * 2, b1 = b0 + 1;
  float a0[4] = {0, 0, 0, 0}, a1[4] = {0, 0, 0, 0};
  for (int i = 0; i < INXv; ++i) {
    const float xa = xts[i][b0], xb = xts[i][b1];
    const float ga = g2s[i][b0], gb = g2s[i][b1];
    const float4 w0 = *(const float4*)&Ws[i * HIDv + og * 4];
    const float4 w1 = *(const float4*)&Ws[INXv * HIDv + i * HIDv + og * 4];
    a0[0] += xa * w0.x + ga * w1.x; a0[1] += xa * w0.y + ga * w1.y;
    a0[2] += xa * w0.z + ga * w1.z; a0[3] += xa * w0.w + ga * w1.w;
    a1[0] += xb * w0.x + gb * w1.x; a1[1] += xb * w0.y + gb * w1.y;
    a1[2] += xb * w0.z + gb * w1.z; a1[3] += xb * w0.w + gb * w1.w;
  }
  {
    const float* t0 = TB + (((size_t)g * Bv + b0) * Tv + t) * HIDv + og * 4;
    const float* t1 = TB + (((size_t)g * Bv + b1) * Tv + t) * HIDv + og * 4;
#pragma unroll
    for (int j = 0; j < 4; ++j) { a0[j] += t0[j]; a1[j] += t1[j]; }
  }
  float s0 = a0[0] + a0[1] + a0[2] + a0[3];
  float s1 = a1[0] + a1[1] + a1[2] + a1[3];
#pragma unroll
  for (int msk = 1; msk < 16; msk <<= 1) { s0 += __shfl_xor(s0, msk); s1 += __shfl_xor(s1, msk); }
  const float mu0 = s0 * (1.f / 64.f), mu1 = s1 * (1.f / 64.f);
  float v0 = 0.f, v1 = 0.f;
#pragma unroll
  for (int j = 0; j < 4; ++j) { const float c0 = a0[j] - mu0, c1 = a1[j] - mu1; v0 += c0 * c0; v1 += c1 * c1; }
#pragma unroll
  for (int msk = 1; msk < 16; msk <<= 1) { v0 += __shfl_xor(v0, msk); v1 += __shfl_xor(v1, msk); }
  const float rs0 = rsqrtf(v0 * (1.f / 64.f) + 1e-5f);
  const float rs1 = rsqrtf(v1 * (1.f / 64.f) + 1e-5f);
  float q0[4], q1[4];
#pragma unroll
  for (int j = 0; j < 4; ++j) {
    const float gg = oln_g[g * HIDv + og * 4 + j], bb = oln_b[g * HIDv + og * 4 + j];
    q0[j] = (a0[j] - mu0) * rs0 * gg + bb;
    q1[j] = (a1[j] - mu1) * rs1 * gg + bb;
  }
  float m0r = -1e30f, m1r = -1e30f, d0 = 0.f, d1 = 0.f;
  float o0[4] = {0, 0, 0, 0}, o1[4] = {0, 0, 0, 0};
  for (int k = 0; k <= t; ++k) {
    const float4 kv0 = *(const float4*)&states[(((size_t)k * Bv + b0) * Nv + n) * HIDv + og * 4];
    const float4 kv1 = *(const float4*)&states[(((size_t)k * Bv + b1) * Nv + n) * HIDv + og * 4];
    float sc0 = q0[0] * kv0.x + q0[1] * kv0.y + q0[2] * kv0.z + q0[3] * kv0.w;
    float sc1 = q1[0] * kv1.x + q1[1] * kv1.y + q1[2] * kv1.z + q1[3] * kv1.w;
    sc0 += __shfl_xor(sc0, 1); sc0 += __shfl_xor(sc0, 2);
    sc1 += __shfl_xor(sc1, 1); sc1 += __shfl_xor(sc1, 2);
    sc0 *= 0.25f; sc1 *= 0.25f;
    const float mn0 = fmaxf(m0r, sc0), mn1 = fmaxf(m1r, sc1);
    const float f0 = __expf(m0r - mn0), f1 = __expf(m1r - mn1);
    const float p0 = __expf(sc0 - mn0), p1 = __expf(sc1 - mn1);
    m0r = mn0; m1r = mn1;
    d0 = d0 * f0 + p0; d1 = d1 * f1 + p1;
    o0[0] = o0[0] * f0 + p0 * kv0.x; o0[1] = o0[1] * f0 + p0 * kv0.y;
    o0[2] = o0[2] * f0 + p0 * kv0.z; o0[3] = o0[3] * f0 + p0 * kv0.w;
    o1[0] = o1[0] * f1 + p1 * kv1.x; o1[1] = o1[1] * f1 + p1 * kv1.y;
    o1[2] = o1[2] * f1 + p1 * kv1.z; o1[3] = o1[3] * f1 + p1 * kv1.w;
  }
  const float ro0 = 1.f / d0, ro1 = 1.f / d1;
  float pre0[4], pre1[4];
#pragma unroll
  for (int j = 0; j < 4; ++j) { pre0[j] = a0[j] + o0[j] * ro0; pre1[j] = a1[j] + o1[j] * ro1; }

  const size_t off0 = ((size_t)b0 * Nv + n) * HIDv + og * 4;
  const size_t off1 = ((size_t)b1 * Nv + n) * HIDv + og * 4;
  if (g == 0) {
    const float4 st0 = *(const float4*)&stcur[off0];
    const float4 st1 = *(const float4*)&stcur[off1];
    float4 w0, w1;
    w0.x = sigmoidf_(pre0[0]) * st0.x; w0.y = sigmoidf_(pre0[1]) * st0.y;
    w0.z = sigmoidf_(pre0[2]) * st0.z; w0.w = sigmoidf_(pre0[3]) * st0.w;
    w1.x = sigmoidf_(pre1[0]) * st1.x; w1.y = sigmoidf_(pre1[1]) * st1.y;
    w1.z = sigmoidf_(pre1[2]) * st1.z; w1.w = sigmoidf_(pre1[3]) * st1.w;
    *(float4*)&zs[off0] = w0; *(float4*)&zs[off1] = w1;
  } else if (g == 1) {
    float4 w0, w1;
    w0.x = sigmoidf_(pre0[0]); w0.y = sigmoidf_(pre0[1]);
    w0.z = sigmoidf_(pre0[2]); w0.w = sigmoidf_(pre0[3]);
    w1.x = sigmoidf_(pre1[0]); w1.y = sigmoidf_(pre1[1]);
    w1.z = sigmoidf_(pre1[2]); w1.w = sigmoidf_(pre1[3]);
    *(float4*)&rb[off0] = w0; *(float4*)&rb[off1] = w1;
  } else {
    const float4 st0 = *(const float4*)&stcur[off0];
    const float4 st1 = *(const float4*)&stcur[off1];
    const float4 r0 = *(const float4*)&rb[off0];
    const float4 r1 = *(const float4*)&rb[off1];
    float4 w0, w1;
    w0.x = r0.x * st0.x + (1.f - r0.x) * tanhf(pre0[0]);
    w0.y = r0.y * st0.y + (1.f - r0.y) * tanhf(pre0[1]);
    w0.z = r0.z * st0.z + (1.f - r0.z) * tanhf(pre0[2]);
    w0.w = r0.w * st0.w + (1.f - r0.w) * tanhf(pre0[3]);
    w1.x = r1.x * st1.x + (1.f - r1.x) * tanhf(pre1[0]);
    w1.y = r1.y * st1.y + (1.f - r1.y) * tanhf(pre1[1]);
    w1.z = r1.z * st1.z + (1.f - r1.z) * tanhf(pre1[2]);
    w1.w = r1.w * st1.w + (1.f - r1.w) * tanhf(pre1[3]);
    *(float4*)&hnew[off0] = w0; *(float4*)&hnew[off1] = w1;
  }
}

// ---------------------------------------------------------------------------
__global__ __launch_bounds__(256) void k_pred(const float* __restrict__ states,
                                              const float* __restrict__ pw,
                                              const float* __restrict__ pb,
                                              float* __restrict__ out) {
  __shared__ float pws[OUTv * CSv * HIDv];
  __shared__ float pbs[OUTv];
  const int tid = threadIdx.x;
  for (int j = tid; j < OUTv * CSv * HIDv; j += 256) pws[j] = pw[j];
  if (tid < OUTv) pbs[tid] = pb[tid];
  __syncthreads();
  const int n = blockIdx.x * 256 + tid;
  const int b = blockIdx.y;
  const float* s0p = &states[(((size_t)(Tv - 1) * Bv + b) * Nv + n) * HIDv];
  const float* s1p = &states[(((size_t)Tv * Bv + b) * Nv + n) * HIDv];
  float4 va[16], vb[16];
#pragma unroll
  for (int j = 0; j < 16; ++j) {
    va[j] = *(const float4*)&s0p[j * 4];
    vb[j] = *(const float4*)&s1p[j * 4];
  }
#pragma unroll
  for (int o = 0; o < OUTv; ++o) {
    float acc = pbs[o];
    const float* w0 = &pws[(o * CSv + 0) * HIDv];
    const float* w1 = &pws[(o * CSv + 1) * HIDv];
#pragma unroll
    for (int j = 0; j < 16; ++j) {
      acc += va[j].x * w0[j * 4 + 0] + va[j].y * w0[j * 4 + 1] +
             va[j].z * w0[j * 4 + 2] + va[j].w * w0[j * 4 + 3];
      acc += vb[j].x * w1[j * 4 + 0] + vb[j].y * w1[j * 4 + 1] +
             vb[j].z * w1[j * 4 + 2] + vb[j].w * w1[j * 4 + 3];
    }
    out[((size_t)b * OUTv + o) * Nv + n] = acc;
  }
}

// ---------------------------------------------------------------------------
extern "C" void kernel_launch(void* const* d_in, const int* in_sizes, int n_in,
                              void* d_out, int out_size, void* d_ws, size_t ws_size,
                              hipStream_t stream) {
  (void)in_sizes; (void)n_in; (void)out_size; (void)ws_size;
  const float* x        = (const float*)d_in[0];
  const float* node_emb = (const float*)d_in[1];
  const float* time_emb = (const float*)d_in[2];
  const float* wp       = (const float*)d_in[3];
  const float* bp       = (const float*)d_in[4];
  const float* gcn_g    = (const float*)d_in[5];
  const float* gcn_b    = (const float*)d_in[6];
  const float* out_g    = (const float*)d_in[7];
  const float* out_b    = (const float*)d_in[8];
  const float* pred_w   = (const float*)d_in[9];
  const float* pred_b   = (const float*)d_in[10];

  float* ws = (float*)d_ws;
  float* W   = ws;                                            // 13172736
  float* TB  = W   + (size_t)3 * Nv * 2 * INXv * HIDv;        // 73728
  float* ST  = TB  + (size_t)3 * Bv * Tv * HIDv;              // 13631488
  float* XG  = ST  + (size_t)(Tv + 1) * Bv * Nv * HIDv;       // 2359296
  float* ZS  = XG  + (size_t)2 * Bv * Nv * 72;                // 1048576
  float* RB  = ZS  + (size_t)Bv * Nv * HIDv;                  // 1048576
  float* EMB = RB  + (size_t)Bv * Nv * HIDv;                  // 9437184

  hipMemsetAsync(ST, 0, (size_t)Bv * Nv * HIDv * sizeof(float), stream);
  k_emb<<<dim3(Nv / 128, Tv, Bv), 384, 0, stream>>>(node_emb, time_emb, gcn_g, gcn_b, EMB);
  k_wpre<<<dim3(Nv, 3), 256, 0, stream>>>(node_emb, wp, W);
  k_tb<<<dim3(Bv * Tv, 3), 64, 0, stream>>>(time_emb, bp, TB);

  for (int t = 0; t < Tv; ++t) {
    float* st_t  = ST + (size_t)t * Bv * Nv * HIDv;
    float* st_t1 = st_t + (size_t)Bv * Nv * HIDv;
    k_gatt<<<dim3(Nv / 64, Bv, 2), 512, 0, stream>>>(x, EMB, st_t, XG, t, 0);
    k_k2<<<dim3(Nv, 1, 2), 256, 0, stream>>>(x, W, TB, out_g, out_b, XG,
                                             st_t, ST, st_t, ZS, RB, st_t1, t, 0);
    k_gatt<<<dim3(Nv / 64, Bv, 1), 512, 0, stream>>>(x, EMB, ZS, XG, t, 2);
    k_k2<<<dim3(Nv, 1, 1), 256, 0, stream>>>(x, W, TB, out_g, out_b, XG,
                                             ZS, ST, st_t, ZS, RB, st_t1, t, 2);
  }
  k_pred<<<dim3(Nv / 256, Bv), 256, 0, stream>>>(ST, pred_w, pred_b, (float*)d_out);
}

// Round 3
// 1986.697 us; speedup vs baseline: 1.1751x; 1.0673x over previous
//
#include <hip/hip_runtime.h>
#include <math.h>

#define Bv   32
#define Tv   12
#define Nv   512
#define DINv 3
#define DEv  16
#define HIDv 64
#define INXv 67   // DIN + HID
#define CSv  2
#define OUTv 12

typedef __attribute__((ext_vector_type(8))) short bf16x8;
typedef __attribute__((ext_vector_type(4))) float f32x4;

__device__ __forceinline__ float sigmoidf_(float x) { return 1.0f / (1.0f + __expf(-x)); }

__device__ __forceinline__ unsigned short f2bf(float f) {
  unsigned u = __float_as_uint(f);
  unsigned r = (u + 0x7FFFu + ((u >> 16) & 1u)) >> 16;
  return (unsigned short)r;
}
__device__ __forceinline__ float bf2f(unsigned short h) {
  return __uint_as_float(((unsigned)h) << 16);
}

// ---------------------------------------------------------------------------
// embp[g][t][b][n][0..15]=bf16 hi of LN'd emb, [16..31]=bf16 lo.
// grid (Nv/128, Tv, Bv), block 384 (3 gates x 128 nodes)
__global__ __launch_bounds__(384) void k_emb(const float* __restrict__ node_emb,
                                             const float* __restrict__ te,
                                             const float* __restrict__ lng,
                                             const float* __restrict__ lnb,
                                             unsigned short* __restrict__ embp) {
  const int t = blockIdx.y, b = blockIdx.z;
  const int g = threadIdx.x >> 7;
  const int nl = threadIdx.x & 127;
  const int n = blockIdx.x * 128 + nl;
  float v[16];
  float mu = 0.f;
#pragma unroll
  for (int d = 0; d < 16; ++d) {
    v[d] = node_emb[n * 16 + d] + te[(b * Tv + t) * 16 + d];
    mu += v[d];
  }
  mu *= 0.0625f;
  float var = 0.f;
#pragma unroll
  for (int d = 0; d < 16; ++d) { const float c = v[d] - mu; var += c * c; }
  var *= 0.0625f;
  const float rs = rsqrtf(var + 1e-12f);
  unsigned short hi[16], lo[16];
#pragma unroll
  for (int d = 0; d < 16; ++d) {
    const float e = (v[d] - mu) * rs * lng[g * 16 + d] + lnb[g * 16 + d];
    hi[d] = f2bf(e);
    lo[d] = f2bf(e - bf2f(hi[d]));
  }
  unsigned w[16];
#pragma unroll
  for (int d = 0; d < 8; ++d) {
    w[d] = (unsigned)hi[2 * d] | ((unsigned)hi[2 * d + 1] << 16);
    w[8 + d] = (unsigned)lo[2 * d] | ((unsigned)lo[2 * d + 1] << 16);
  }
  uint4* op = (uint4*)(embp + ((((size_t)g * Tv + t) * Bv + b) * Nv + n) * 32);
  op[0] = make_uint4(w[0], w[1], w[2], w[3]);
  op[1] = make_uint4(w[4], w[5], w[6], w[7]);
  op[2] = make_uint4(w[8], w[9], w[10], w[11]);
  op[3] = make_uint4(w[12], w[13], w[14], w[15]);
}

// ---------------------------------------------------------------------------
// W[g][n][k][i][o] = sum_d node_emb[n][d] * wp[g][d][k][i][o]
__global__ __launch_bounds__(256) void k_wpre(const float* __restrict__ node_emb,
                                              const float* __restrict__ wp,
                                              float* __restrict__ W) {
  const int g = blockIdx.y;
  const int n = blockIdx.x;
  __shared__ float ne[DEv];
  if (threadIdx.x < DEv) ne[threadIdx.x] = node_emb[n * DEv + threadIdx.x];
  __syncthreads();
  const float* wpg = wp + (size_t)g * (DEv * 2 * INXv * HIDv);
  float* Wo = W + ((size_t)g * Nv + n) * (2 * INXv * HIDv);
  for (int j = threadIdx.x; j < 2 * INXv * HIDv; j += 256) {
    float s = 0.f;
#pragma unroll
    for (int d = 0; d < DEv; ++d) s += ne[d] * wpg[(size_t)d * (2 * INXv * HIDv) + j];
    Wo[j] = s;
  }
}

// TB[g][b][t][o]
__global__ __launch_bounds__(64) void k_tb(const float* __restrict__ te,
                                           const float* __restrict__ bp,
                                           float* __restrict__ TB) {
  const int g = blockIdx.y;
  const int bt = blockIdx.x;
  const int b = bt / Tv, t = bt % Tv;
  const int o = threadIdx.x;
  float s = 0.f;
#pragma unroll
  for (int d = 0; d < DEv; ++d) s += te[(b * Tv + t) * DEv + d] * bp[(g * DEv + d) * HIDv + o];
  TB[(((size_t)g * Bv + b) * Tv + t) * HIDv + o] = s;
}

// ---------------------------------------------------------------------------
// Graph attention via split-bf16 MFMA. Block 256 thr = 4 waves, 64 rows.
// xg2 row stride = 80 floats (cols 0..63 state-part, 64..66 x-part).
// grid (Nv/64, Bv, ngates)
__global__ __launch_bounds__(256, 2) void k_gatt(const float* __restrict__ x,
                                                 const unsigned short* __restrict__ embp,
                                                 const float* __restrict__ src,
                                                 float* __restrict__ xg2,
                                                 int t, int g0) {
  const int z = blockIdx.z, g = g0 + z;
  const int b = blockIdx.y;
  const int n0 = blockIdx.x * 64;
  const int tid = threadIdx.x;
  const int w = tid >> 6, lane = tid & 63;
  const int l15 = lane & 15, g4 = lane >> 4;

  __shared__ unsigned short e_lds[32][40];   // [m][k-packed: 0..15 hi, 16..31 lo]
  __shared__ unsigned short vhi[80][40];     // [c][m]
  __shared__ unsigned short vlo[80][40];
  __shared__ unsigned short plh[4][16][40];  // per-wave P hi [r][m]
  __shared__ unsigned short pll[4][16][40];

  // zero the pad cols (c=67..79) once
  for (int i = tid; i < 13 * 40; i += 256) {
    vhi[67 + i / 40][i % 40] = 0;
    vlo[67 + i / 40][i % 40] = 0;
  }

  const unsigned short* embB = embp + ((((size_t)g * Tv + t) * Bv + b) * Nv) * 32;
  const float* srcb = src + (size_t)b * Nv * HIDv;
  const float* xb = x + ((size_t)b * Tv + t) * (size_t)(Nv * DINv);

  // Q fragments (loop-invariant): A=[Qhi|Qhi] and [Qlo|Qlo]
  const int qrow = n0 + w * 16 + l15;
  const bf16x8 qhi = *(const bf16x8*)(embB + (size_t)qrow * 32 + (g4 & 1) * 8);
  const bf16x8 qlo = *(const bf16x8*)(embB + (size_t)qrow * 32 + 16 + (g4 & 1) * 8);

  f32x4 acc[5];
#pragma unroll
  for (int i = 0; i < 5; ++i) acc[i] = (f32x4){0.f, 0.f, 0.f, 0.f};
  float mr[4] = {-1e30f, -1e30f, -1e30f, -1e30f};
  float dn[4] = {0.f, 0.f, 0.f, 0.f};

  for (int m0 = 0; m0 < Nv; m0 += 32) {
    __syncthreads();
    // stage E tile (already split-packed): 32 rows x 64B
    if (tid < 128) {
      const int m = tid & 31, kq = tid >> 5;
      *(uint4*)&e_lds[m][kq * 8] = *(const uint4*)(embB + (size_t)(m0 + m) * 32 + kq * 8);
    }
    // stage V tile transposed + split: vhi/vlo[c][m]
    for (int j = tid; j < 320; j += 256) {
      const int c = j % 80, mq = j / 80;
      if (c < 67) {
        unsigned short h8[8], l8[8];
        if (c < 64) {
#pragma unroll
          for (int u = 0; u < 8; ++u) {
            const float v = srcb[(size_t)(m0 + mq * 8 + u) * HIDv + c];
            const unsigned short h = f2bf(v);
            h8[u] = h; l8[u] = f2bf(v - bf2f(h));
          }
        } else {
#pragma unroll
          for (int u = 0; u < 8; ++u) {
            const float v = xb[(size_t)(m0 + mq * 8 + u) * 3 + (c - 64)];
            const unsigned short h = f2bf(v);
            h8[u] = h; l8[u] = f2bf(v - bf2f(h));
          }
        }
        uint4 ph, pl;
        ph.x = (unsigned)h8[0] | ((unsigned)h8[1] << 16);
        ph.y = (unsigned)h8[2] | ((unsigned)h8[3] << 16);
        ph.z = (unsigned)h8[4] | ((unsigned)h8[5] << 16);
        ph.w = (unsigned)h8[6] | ((unsigned)h8[7] << 16);
        pl.x = (unsigned)l8[0] | ((unsigned)l8[1] << 16);
        pl.y = (unsigned)l8[2] | ((unsigned)l8[3] << 16);
        pl.z = (unsigned)l8[4] | ((unsigned)l8[5] << 16);
        pl.w = (unsigned)l8[6] | ((unsigned)l8[7] << 16);
        *(uint4*)&vhi[c][mq * 8] = ph;
        *(uint4*)&vlo[c][mq * 8] = pl;
      }
    }
    __syncthreads();

    // scores: S[r][m] for m-tile of 32 (two 16-col frags)
    const bf16x8 eb0 = *(const bf16x8*)&e_lds[l15][g4 * 8];
    const bf16x8 eb1 = *(const bf16x8*)&e_lds[16 + l15][g4 * 8];
    f32x4 s0 = (f32x4){0.f, 0.f, 0.f, 0.f};
    f32x4 s1 = (f32x4){0.f, 0.f, 0.f, 0.f};
    s0 = __builtin_amdgcn_mfma_f32_16x16x32_bf16(qhi, eb0, s0, 0, 0, 0);
    s0 = __builtin_amdgcn_mfma_f32_16x16x32_bf16(qlo, eb0, s0, 0, 0, 0);
    s1 = __builtin_amdgcn_mfma_f32_16x16x32_bf16(qhi, eb1, s1, 0, 0, 0);
    s1 = __builtin_amdgcn_mfma_f32_16x16x32_bf16(qlo, eb1, s1, 0, 0, 0);

    // online softmax per C-row (reg j); 16-lane group shares a row
#pragma unroll
    for (int j = 0; j < 4; ++j) {
      float tm = fmaxf(s0[j], s1[j]);
      tm = fmaxf(tm, __shfl_xor(tm, 1));
      tm = fmaxf(tm, __shfl_xor(tm, 2));
      tm = fmaxf(tm, __shfl_xor(tm, 4));
      tm = fmaxf(tm, __shfl_xor(tm, 8));
      const float mn = fmaxf(mr[j], tm);
      const float sc = __expf(mr[j] - mn);
      mr[j] = mn;
      const float p0 = __expf(s0[j] - mn);
      const float p1 = __expf(s1[j] - mn);
      float ps = p0 + p1;
      ps += __shfl_xor(ps, 1);
      ps += __shfl_xor(ps, 2);
      ps += __shfl_xor(ps, 4);
      ps += __shfl_xor(ps, 8);
      dn[j] = dn[j] * sc + ps;
#pragma unroll
      for (int tl = 0; tl < 5; ++tl) acc[tl][j] *= sc;
      const int r = g4 * 4 + j;
      const unsigned short h0 = f2bf(p0);
      const unsigned short h1 = f2bf(p1);
      plh[w][r][l15] = h0;
      pll[w][r][l15] = f2bf(p0 - bf2f(h0));
      plh[w][r][16 + l15] = h1;
      pll[w][r][16 + l15] = f2bf(p1 - bf2f(h1));
    }

    // P as A-operand (transposed via per-wave LDS)
    const bf16x8 pAh = *(const bf16x8*)&plh[w][l15][g4 * 8];
    const bf16x8 pAl = *(const bf16x8*)&pll[w][l15][g4 * 8];

#pragma unroll
    for (int tl = 0; tl < 5; ++tl) {
      const bf16x8 vh = *(const bf16x8*)&vhi[tl * 16 + l15][g4 * 8];
      const bf16x8 vl = *(const bf16x8*)&vlo[tl * 16 + l15][g4 * 8];
      acc[tl] = __builtin_amdgcn_mfma_f32_16x16x32_bf16(pAh, vh, acc[tl], 0, 0, 0);
      acc[tl] = __builtin_amdgcn_mfma_f32_16x16x32_bf16(pAh, vl, acc[tl], 0, 0, 0);
      acc[tl] = __builtin_amdgcn_mfma_f32_16x16x32_bf16(pAl, vh, acc[tl], 0, 0, 0);
    }
  }

  float* outB = xg2 + (((size_t)z * Bv + b) * Nv) * 80;
#pragma unroll
  for (int j = 0; j < 4; ++j) {
    const float r = 1.f / dn[j];
    const int n = n0 + w * 16 + g4 * 4 + j;
#pragma unroll
    for (int tl = 0; tl < 5; ++tl) {
      const int c = tl * 16 + l15;
      if (c < 67) outB[(size_t)n * 80 + c] = acc[tl][j] * r;
    }
  }
}

// ---------------------------------------------------------------------------
// K2: gout = xt@W0[n] + xg2@W1[n] + tb ; q=LN(gout); temporal attn; gate.
// grid (Nv, 1, ngates), block 256
__global__ __launch_bounds__(256) void k_k2(const float* __restrict__ x,
                                            const float* __restrict__ Wb,
                                            const float* __restrict__ TB,
                                            const float* __restrict__ oln_g,
                                            const float* __restrict__ oln_b,
                                            const float* __restrict__ xg2,
                                            const float* __restrict__ srcst,
                                            const float* __restrict__ states,
                                            const float* __restrict__ stcur,
                                            float* __restrict__ zs,
                                            float* __restrict__ rb,
                                            float* __restrict__ hnew,
                                            int t, int g0) {
  const int zb = blockIdx.z;
  const int g = g0 + zb;
  const int n = blockIdx.x;
  __shared__ float Ws[2 * INXv * HIDv];
  __shared__ float xts[INXv][34];
  __shared__ float g2s[INXv][34];
  const int tid = threadIdx.x;

  const float* Wp = Wb + ((size_t)g * Nv + n) * (2 * INXv * HIDv);
  for (int j = tid; j < (2 * INXv * HIDv) / 4; j += 256)
    ((float4*)Ws)[j] = ((const float4*)Wp)[j];
  {
    const int b = tid >> 3, cc = tid & 7;
    const float* sp = &srcst[((size_t)b * Nv + n) * HIDv + cc * 8];
    const float4 a = *(const float4*)sp;
    const float4 c = *(const float4*)(sp + 4);
    xts[3 + cc * 8 + 0][b] = a.x; xts[3 + cc * 8 + 1][b] = a.y;
    xts[3 + cc * 8 + 2][b] = a.z; xts[3 + cc * 8 + 3][b] = a.w;
    xts[3 + cc * 8 + 4][b] = c.x; xts[3 + cc * 8 + 5][b] = c.y;
    xts[3 + cc * 8 + 6][b] = c.z; xts[3 + cc * 8 + 7][b] = c.w;
    const float* gp = &xg2[(((size_t)zb * Bv + b) * Nv + n) * 80 + cc * 8];
    const float4 p = *(const float4*)gp;
    const float4 r2 = *(const float4*)(gp + 4);
    g2s[3 + cc * 8 + 0][b] = p.x;  g2s[3 + cc * 8 + 1][b] = p.y;
    g2s[3 + cc * 8 + 2][b] = p.z;  g2s[3 + cc * 8 + 3][b] = p.w;
    g2s[3 + cc * 8 + 4][b] = r2.x; g2s[3 + cc * 8 + 5][b] = r2.y;
    g2s[3 + cc * 8 + 6][b] = r2.z; g2s[3 + cc * 8 + 7][b] = r2.w;
  }
  if (tid < Bv) {
    const int b = tid;
    const float* xp = &x[(((size_t)b * Tv + t) * Nv + n) * DINv];
    xts[0][b] = xp[0]; xts[1][b] = xp[1]; xts[2][b] = xp[2];
    const float* gp = &xg2[(((size_t)zb * Bv + b) * Nv + n) * 80 + 64];
    g2s[0][b] = gp[0]; g2s[1][b] = gp[1]; g2s[2][b] = gp[2];
  }
  __syncthreads();

  const int og = tid & 15, bp = tid >> 4;
  const int b0 = bp * 2, b1 = b0 + 1;
  float a0[4] = {0, 0, 0, 0}, a1[4] = {0, 0, 0, 0};
  for (int i = 0; i < INXv; ++i) {
    const float xa = xts[i][b0], xb = xts[i][b1];
    const float ga = g2s[i][b0], gb = g2s[i][b1];
    const float4 w0 = *(const float4*)&Ws[i * HIDv + og * 4];
    const float4 w1 = *(const float4*)&Ws[INXv * HIDv + i * HIDv + og * 4];
    a0[0] += xa * w0.x + ga * w1.x; a0[1] += xa * w0.y + ga * w1.y;
    a0[2] += xa * w0.z + ga * w1.z; a0[3] += xa * w0.w + ga * w1.w;
    a1[0] += xb * w0.x + gb * w1.x; a1[1] += xb * w0.y + gb * w1.y;
    a1[2] += xb * w0.z + gb * w1.z; a1[3] += xb * w0.w + gb * w1.w;
  }
  {
    const float* t0 = TB + (((size_t)g * Bv + b0) * Tv + t) * HIDv + og * 4;
    const float* t1 = TB + (((size_t)g * Bv + b1) * Tv + t) * HIDv + og * 4;
#pragma unroll
    for (int j = 0; j < 4; ++j) { a0[j] += t0[j]; a1[j] += t1[j]; }
  }
  float s0 = a0[0] + a0[1] + a0[2] + a0[3];
  float s1 = a1[0] + a1[1] + a1[2] + a1[3];
#pragma unroll
  for (int msk = 1; msk < 16; msk <<= 1) { s0 += __shfl_xor(s0, msk); s1 += __shfl_xor(s1, msk); }
  const float mu0 = s0 * (1.f / 64.f), mu1 = s1 * (1.f / 64.f);
  float v0 = 0.f, v1 = 0.f;
#pragma unroll
  for (int j = 0; j < 4; ++j) { const float c0 = a0[j] - mu0, c1 = a1[j] - mu1; v0 += c0 * c0; v1 += c1 * c1; }
#pragma unroll
  for (int msk = 1; msk < 16; msk <<= 1) { v0 += __shfl_xor(v0, msk); v1 += __shfl_xor(v1, msk); }
  const float rs0 = rsqrtf(v0 * (1.f / 64.f) + 1e-5f);
  const float rs1 = rsqrtf(v1 * (1.f / 64.f) + 1e-5f);
  float q0[4], q1[4];
#pragma unroll
  for (int j = 0; j < 4; ++j) {
    const float gg = oln_g[g * HIDv + og * 4 + j], bb = oln_b[g * HIDv + og * 4 + j];
    q0[j] = (a0[j] - mu0) * rs0 * gg + bb;
    q1[j] = (a1[j] - mu1) * rs1 * gg + bb;
  }
  float m0r = -1e30f, m1r = -1e30f, d0 = 0.f, d1 = 0.f;
  float o0[4] = {0, 0, 0, 0}, o1[4] = {0, 0, 0, 0};
  for (int k = 0; k <= t; ++k) {
    const float4 kv0 = *(const float4*)&states[(((size_t)k * Bv + b0) * Nv + n) * HIDv + og * 4];
    const float4 kv1 = *(const float4*)&states[(((size_t)k * Bv + b1) * Nv + n) * HIDv + og * 4];
    float sc0 = q0[0] * kv0.x + q0[1] * kv0.y + q0[2] * kv0.z + q0[3] * kv0.w;
    float sc1 = q1[0] * kv1.x + q1[1] * kv1.y + q1[2] * kv1.z + q1[3] * kv1.w;
    sc0 += __shfl_xor(sc0, 1); sc0 += __shfl_xor(sc0, 2);
    sc1 += __shfl_xor(sc1, 1); sc1 += __shfl_xor(sc1, 2);
    sc0 *= 0.25f; sc1 *= 0.25f;
    const float mn0 = fmaxf(m0r, sc0), mn1 = fmaxf(m1r, sc1);
    const float f0 = __expf(m0r - mn0), f1 = __expf(m1r - mn1);
    const float p0 = __expf(sc0 - mn0), p1 = __expf(sc1 - mn1);
    m0r = mn0; m1r = mn1;
    d0 = d0 * f0 + p0; d1 = d1 * f1 + p1;
    o0[0] = o0[0] * f0 + p0 * kv0.x; o0[1] = o0[1] * f0 + p0 * kv0.y;
    o0[2] = o0[2] * f0 + p0 * kv0.z; o0[3] = o0[3] * f0 + p0 * kv0.w;
    o1[0] = o1[0] * f1 + p1 * kv1.x; o1[1] = o1[1] * f1 + p1 * kv1.y;
    o1[2] = o1[2] * f1 + p1 * kv1.z; o1[3] = o1[3] * f1 + p1 * kv1.w;
  }
  const float ro0 = 1.f / d0, ro1 = 1.f / d1;
  float pre0[4], pre1[4];
#pragma unroll
  for (int j = 0; j < 4; ++j) { pre0[j] = a0[j] + o0[j] * ro0; pre1[j] = a1[j] + o1[j] * ro1; }

  const size_t off0 = ((size_t)b0 * Nv + n) * HIDv + og * 4;
  const size_t off1 = ((size_t)b1 * Nv + n) * HIDv + og * 4;
  if (g == 0) {
    const float4 st0 = *(const float4*)&stcur[off0];
    const float4 st1 = *(const float4*)&stcur[off1];
    float4 w0, w1;
    w0.x = sigmoidf_(pre0[0]) * st0.x; w0.y = sigmoidf_(pre0[1]) * st0.y;
    w0.z = sigmoidf_(pre0[2]) * st0.z; w0.w = sigmoidf_(pre0[3]) * st0.w;
    w1.x = sigmoidf_(pre1[0]) * st1.x; w1.y = sigmoidf_(pre1[1]) * st1.y;
    w1.z = sigmoidf_(pre1[2]) * st1.z; w1.w = sigmoidf_(pre1[3]) * st1.w;
    *(float4*)&zs[off0] = w0; *(float4*)&zs[off1] = w1;
  } else if (g == 1) {
    float4 w0, w1;
    w0.x = sigmoidf_(pre0[0]); w0.y = sigmoidf_(pre0[1]);
    w0.z = sigmoidf_(pre0[2]); w0.w = sigmoidf_(pre0[3]);
    w1.x = sigmoidf_(pre1[0]); w1.y = sigmoidf_(pre1[1]);
    w1.z = sigmoidf_(pre1[2]); w1.w = sigmoidf_(pre1[3]);
    *(float4*)&rb[off0] = w0; *(float4*)&rb[off1] = w1;
  } else {
    const float4 st0 = *(const float4*)&stcur[off0];
    const float4 st1 = *(const float4*)&stcur[off1];
    const float4 r0 = *(const float4*)&rb[off0];
    const float4 r1 = *(const float4*)&rb[off1];
    float4 w0, w1;
    w0.x = r0.x * st0.x + (1.f - r0.x) * tanhf(pre0[0]);
    w0.y = r0.y * st0.y + (1.f - r0.y) * tanhf(pre0[1]);
    w0.z = r0.z * st0.z + (1.f - r0.z) * tanhf(pre0[2]);
    w0.w = r0.w * st0.w + (1.f - r0.w) * tanhf(pre0[3]);
    w1.x = r1.x * st1.x + (1.f - r1.x) * tanhf(pre1[0]);
    w1.y = r1.y * st1.y + (1.f - r1.y) * tanhf(pre1[1]);
    w1.z = r1.z * st1.z + (1.f - r1.z) * tanhf(pre1[2]);
    w1.w = r1.w * st1.w + (1.f - r1.w) * tanhf(pre1[3]);
    *(float4*)&hnew[off0] = w0; *(float4*)&hnew[off1] = w1;
  }
}

// ---------------------------------------------------------------------------
__global__ __launch_bounds__(256) void k_pred(const float* __restrict__ states,
                                              const float* __restrict__ pw,
                                              const float* __restrict__ pb,
                                              float* __restrict__ out) {
  __shared__ float pws[OUTv * CSv * HIDv];
  __shared__ float pbs[OUTv];
  const int tid = threadIdx.x;
  for (int j = tid; j < OUTv * CSv * HIDv; j += 256) pws[j] = pw[j];
  if (tid < OUTv) pbs[tid] = pb[tid];
  __syncthreads();
  const int n = blockIdx.x * 256 + tid;
  const int b = blockIdx.y;
  const float* s0p = &states[(((size_t)(Tv - 1) * Bv + b) * Nv + n) * HIDv];
  const float* s1p = &states[(((size_t)Tv * Bv + b) * Nv + n) * HIDv];
  float4 va[16], vb[16];
#pragma unroll
  for (int j = 0; j < 16; ++j) {
    va[j] = *(const float4*)&s0p[j * 4];
    vb[j] = *(const float4*)&s1p[j * 4];
  }
#pragma unroll
  for (int o = 0; o < OUTv; ++o) {
    float acc = pbs[o];
    const float* w0 = &pws[(o * CSv + 0) * HIDv];
    const float* w1 = &pws[(o * CSv + 1) * HIDv];
#pragma unroll
    for (int j = 0; j < 16; ++j) {
      acc += va[j].x * w0[j * 4 + 0] + va[j].y * w0[j * 4 + 1] +
             va[j].z * w0[j * 4 + 2] + va[j].w * w0[j * 4 + 3];
      acc += vb[j].x * w1[j * 4 + 0] + vb[j].y * w1[j * 4 + 1] +
             vb[j].z * w1[j * 4 + 2] + vb[j].w * w1[j * 4 + 3];
    }
    out[((size_t)b * OUTv + o) * Nv + n] = acc;
  }
}

// ---------------------------------------------------------------------------
extern "C" void kernel_launch(void* const* d_in, const int* in_sizes, int n_in,
                              void* d_out, int out_size, void* d_ws, size_t ws_size,
                              hipStream_t stream) {
  (void)in_sizes; (void)n_in; (void)out_size; (void)ws_size;
  const float* x        = (const float*)d_in[0];
  const float* node_emb = (const float*)d_in[1];
  const float* time_emb = (const float*)d_in[2];
  const float* wp       = (const float*)d_in[3];
  const float* bp       = (const float*)d_in[4];
  const float* gcn_g    = (const float*)d_in[5];
  const float* gcn_b    = (const float*)d_in[6];
  const float* out_g    = (const float*)d_in[7];
  const float* out_b    = (const float*)d_in[8];
  const float* pred_w   = (const float*)d_in[9];
  const float* pred_b   = (const float*)d_in[10];

  float* ws = (float*)d_ws;
  float* W    = ws;                                           // 13172736
  float* TB   = W   + (size_t)3 * Nv * 2 * INXv * HIDv;       // 73728
  float* ST   = TB  + (size_t)3 * Bv * Tv * HIDv;             // 13631488
  float* XG   = ST  + (size_t)(Tv + 1) * Bv * Nv * HIDv;      // 2*32*512*80 = 2621440
  float* ZS   = XG  + (size_t)2 * Bv * Nv * 80;               // 1048576
  float* RB   = ZS  + (size_t)Bv * Nv * HIDv;                 // 1048576
  unsigned short* EMBp = (unsigned short*)(RB + (size_t)Bv * Nv * HIDv);  // 18.9M u16

  hipMemsetAsync(ST, 0, (size_t)Bv * Nv * HIDv * sizeof(float), stream);
  k_emb<<<dim3(Nv / 128, Tv, Bv), 384, 0, stream>>>(node_emb, time_emb, gcn_g, gcn_b, EMBp);
  k_wpre<<<dim3(Nv, 3), 256, 0, stream>>>(node_emb, wp, W);
  k_tb<<<dim3(Bv * Tv, 3), 64, 0, stream>>>(time_emb, bp, TB);

  for (int t = 0; t < Tv; ++t) {
    float* st_t  = ST + (size_t)t * Bv * Nv * HIDv;
    float* st_t1 = st_t + (size_t)Bv * Nv * HIDv;
    k_gatt<<<dim3(Nv / 64, Bv, 2), 256, 0, stream>>>(x, EMBp, st_t, XG, t, 0);
    k_k2<<<dim3(Nv, 1, 2), 256, 0, stream>>>(x, W, TB, out_g, out_b, XG,
                                             st_t, ST, st_t, ZS, RB, st_t1, t, 0);
    k_gatt<<<dim3(Nv / 64, Bv, 1), 256, 0, stream>>>(x, EMBp, ZS, XG, t, 2);
    k_k2<<<dim3(Nv, 1, 1), 256, 0, stream>>>(x, W, TB, out_g, out_b, XG,
                                             ZS, ST, st_t, ZS, RB, st_t1, t, 2);
  }
  k_pred<<<dim3(Nv / 256, Bv), 256, 0, stream>>>(ST, pred_w, pred_b, (float*)d_out);
}

// Round 4
// 1736.190 us; speedup vs baseline: 1.3447x; 1.1443x over previous
//
#include <hip/hip_runtime.h>
#include <math.h>

#define Bv   32
#define Tv   12
#define Nv   512
#define DINv 3
#define DEv  16
#define HIDv 64
#define INXv 67   // DIN + HID
#define CSv  2
#define OUTv 12
#define WSZ  (2 * INXv * HIDv)   // 8576

typedef __attribute__((ext_vector_type(8))) short bf16x8;
typedef __attribute__((ext_vector_type(4))) float f32x4;

__device__ __forceinline__ float sigmoidf_(float x) { return 1.0f / (1.0f + __expf(-x)); }

__device__ __forceinline__ unsigned short f2bf(float f) {
  unsigned u = __float_as_uint(f);
  unsigned r = (u + 0x7FFFu + ((u >> 16) & 1u)) >> 16;
  return (unsigned short)r;
}
__device__ __forceinline__ float bf2f(unsigned short h) {
  return __uint_as_float(((unsigned)h) << 16);
}

// ---------------------------------------------------------------------------
// embp[g][t][b][n][0..15]=bf16 hi of LN'd emb, [16..31]=bf16 lo.
__global__ __launch_bounds__(384) void k_emb(const float* __restrict__ node_emb,
                                             const float* __restrict__ te,
                                             const float* __restrict__ lng,
                                             const float* __restrict__ lnb,
                                             unsigned short* __restrict__ embp) {
  const int t = blockIdx.y, b = blockIdx.z;
  const int g = threadIdx.x >> 7;
  const int nl = threadIdx.x & 127;
  const int n = blockIdx.x * 128 + nl;
  float v[16];
  float mu = 0.f;
#pragma unroll
  for (int d = 0; d < 16; ++d) {
    v[d] = node_emb[n * 16 + d] + te[(b * Tv + t) * 16 + d];
    mu += v[d];
  }
  mu *= 0.0625f;
  float var = 0.f;
#pragma unroll
  for (int d = 0; d < 16; ++d) { const float c = v[d] - mu; var += c * c; }
  var *= 0.0625f;
  const float rs = rsqrtf(var + 1e-12f);
  unsigned short hi[16], lo[16];
#pragma unroll
  for (int d = 0; d < 16; ++d) {
    const float e = (v[d] - mu) * rs * lng[g * 16 + d] + lnb[g * 16 + d];
    hi[d] = f2bf(e);
    lo[d] = f2bf(e - bf2f(hi[d]));
  }
  unsigned w[16];
#pragma unroll
  for (int d = 0; d < 8; ++d) {
    w[d] = (unsigned)hi[2 * d] | ((unsigned)hi[2 * d + 1] << 16);
    w[8 + d] = (unsigned)lo[2 * d] | ((unsigned)lo[2 * d + 1] << 16);
  }
  uint4* op = (uint4*)(embp + ((((size_t)g * Tv + t) * Bv + b) * Nv + n) * 32);
  op[0] = make_uint4(w[0], w[1], w[2], w[3]);
  op[1] = make_uint4(w[4], w[5], w[6], w[7]);
  op[2] = make_uint4(w[8], w[9], w[10], w[11]);
  op[3] = make_uint4(w[12], w[13], w[14], w[15]);
}

// ---------------------------------------------------------------------------
// W[g][n][k][i][o] = sum_d node_emb[n][d] * wp[g][d][k][i][o]
// grid (34, 3, 4), block 256: thread owns one j, loops 128 n's.
__global__ __launch_bounds__(256) void k_wpre(const float* __restrict__ node_emb,
                                              const float* __restrict__ wp,
                                              float* __restrict__ W) {
  const int g = blockIdx.y;
  const int j = blockIdx.x * 256 + threadIdx.x;
  const int n0 = blockIdx.z * 128;
  if (j >= WSZ) return;
  const float* wpg = wp + (size_t)g * (DEv * WSZ);
  float wr[16];
#pragma unroll
  for (int d = 0; d < 16; ++d) wr[d] = wpg[(size_t)d * WSZ + j];
  float* Wg = W + (size_t)g * Nv * WSZ;
  for (int n = n0; n < n0 + 128; ++n) {
    const float4 e0 = *(const float4*)(node_emb + n * 16);
    const float4 e1 = *(const float4*)(node_emb + n * 16 + 4);
    const float4 e2 = *(const float4*)(node_emb + n * 16 + 8);
    const float4 e3 = *(const float4*)(node_emb + n * 16 + 12);
    float s = e0.x * wr[0] + e0.y * wr[1] + e0.z * wr[2] + e0.w * wr[3]
            + e1.x * wr[4] + e1.y * wr[5] + e1.z * wr[6] + e1.w * wr[7]
            + e2.x * wr[8] + e2.y * wr[9] + e2.z * wr[10] + e2.w * wr[11]
            + e3.x * wr[12] + e3.y * wr[13] + e3.z * wr[14] + e3.w * wr[15];
    Wg[(size_t)n * WSZ + j] = s;
  }
}

// TB[g][b][t][o]
__global__ __launch_bounds__(64) void k_tb(const float* __restrict__ te,
                                           const float* __restrict__ bp,
                                           float* __restrict__ TB) {
  const int g = blockIdx.y;
  const int bt = blockIdx.x;
  const int b = bt / Tv, t = bt % Tv;
  const int o = threadIdx.x;
  float s = 0.f;
#pragma unroll
  for (int d = 0; d < DEv; ++d) s += te[(b * Tv + t) * DEv + d] * bp[(g * DEv + d) * HIDv + o];
  TB[(((size_t)g * Bv + b) * Tv + t) * HIDv + o] = s;
}

// ---------------------------------------------------------------------------
// V prep: Vs[b][plane][c:80][m:512] u16 (plane 0=hi, 1=lo); c 0..63 = state,
// 64..66 = x, 67..79 = 0. grid (4, Bv), block 256.
__global__ __launch_bounds__(256) void k_vprep(const float* __restrict__ src,
                                               const float* __restrict__ x,
                                               unsigned short* __restrict__ Vs,
                                               int t) {
  const int b = blockIdx.y;
  const int m0 = blockIdx.x * 128;
  const int tid = threadIdx.x;
  __shared__ float sl[128][69];
  const float* srcb = src + ((size_t)b * Nv + m0) * HIDv;
  for (int j = tid; j < 2048; j += 256) {
    const int r = j >> 4, c4 = j & 15;
    const float4 v = *(const float4*)(srcb + r * HIDv + c4 * 4);
    sl[r][c4 * 4 + 0] = v.x; sl[r][c4 * 4 + 1] = v.y;
    sl[r][c4 * 4 + 2] = v.z; sl[r][c4 * 4 + 3] = v.w;
  }
  const float* xb = x + (((size_t)b * Tv + t) * Nv + m0) * DINv;
  for (int j = tid; j < 384; j += 256) sl[j / 3][64 + j % 3] = xb[j];
  __syncthreads();
  unsigned short* VsB = Vs + (size_t)b * 2 * 80 * 512;
  for (int j = tid; j < 80 * 128; j += 256) {
    const int m = j & 127, c = j >> 7;
    const float v = (c < 67) ? sl[m][c] : 0.f;
    const unsigned short h = f2bf(v);
    VsB[(size_t)c * 512 + m0 + m] = h;
    VsB[(size_t)(80 + c) * 512 + m0 + m] = f2bf(v - bf2f(h));
  }
}

// ---------------------------------------------------------------------------
// Graph attention, split-bf16 MFMA, no online-max (|s|<=16 since LN'd emb,
// g=1,b=0 => p = exp(s-16) in (0,1]). Block 256 = 4 waves, 64 rows.
// grid (Nv/64, Bv, ngates)
__global__ __launch_bounds__(256) void k_gatt(const unsigned short* __restrict__ embp,
                                              const unsigned short* __restrict__ Vs,
                                              float* __restrict__ xg2,
                                              int t, int g0) {
  const int z = blockIdx.z, g = g0 + z;
  const int b = blockIdx.y;
  const int n0 = blockIdx.x * 64;
  const int tid = threadIdx.x;
  const int w = tid >> 6, lane = tid & 63;
  const int l15 = lane & 15, g4 = lane >> 4;

  __shared__ unsigned short vh[80][40];
  __shared__ unsigned short vl[80][40];
  __shared__ unsigned short ph_[4][16][40];
  __shared__ unsigned short pl_[4][16][40];

  const unsigned short* embB = embp + ((((size_t)g * Tv + t) * Bv + b) * Nv) * 32;
  const unsigned short* VsB = Vs + (size_t)b * 2 * 80 * 512;

  const int qrow = n0 + w * 16 + l15;
  const bf16x8 qhi = *(const bf16x8*)(embB + (size_t)qrow * 32 + (g4 & 1) * 8);
  const bf16x8 qlo = *(const bf16x8*)(embB + (size_t)qrow * 32 + 16 + (g4 & 1) * 8);

  f32x4 acc[5];
#pragma unroll
  for (int i = 0; i < 5; ++i) acc[i] = (f32x4){0.f, 0.f, 0.f, 0.f};
  float dn[4] = {0.f, 0.f, 0.f, 0.f};

  for (int m0 = 0; m0 < Nv; m0 += 32) {
    __syncthreads();
    // stage V tile: 160 rows x 32 m (16B chunks)
    for (int j = tid; j < 640; j += 256) {
      const int chunk = j & 3, r = j >> 2;
      const int c = (r >= 80) ? r - 80 : r;
      const uint4 v = *(const uint4*)(VsB + (size_t)r * 512 + m0 + chunk * 8);
      if (r >= 80) *(uint4*)&vl[c][chunk * 8] = v;
      else         *(uint4*)&vh[c][chunk * 8] = v;
    }
    __syncthreads();

    // scores (exact split product via [hi|lo]-packed K)
    const bf16x8 eb0 = *(const bf16x8*)(embB + (size_t)(m0 + l15) * 32 + g4 * 8);
    const bf16x8 eb1 = *(const bf16x8*)(embB + (size_t)(m0 + 16 + l15) * 32 + g4 * 8);
    f32x4 s0 = (f32x4){0.f, 0.f, 0.f, 0.f};
    f32x4 s1 = (f32x4){0.f, 0.f, 0.f, 0.f};
    s0 = __builtin_amdgcn_mfma_f32_16x16x32_bf16(qhi, eb0, s0, 0, 0, 0);
    s0 = __builtin_amdgcn_mfma_f32_16x16x32_bf16(qlo, eb0, s0, 0, 0, 0);
    s1 = __builtin_amdgcn_mfma_f32_16x16x32_bf16(qhi, eb1, s1, 0, 0, 0);
    s1 = __builtin_amdgcn_mfma_f32_16x16x32_bf16(qlo, eb1, s1, 0, 0, 0);

#pragma unroll
    for (int j = 0; j < 4; ++j) {
      const float p0 = __expf(s0[j] - 16.f);
      const float p1 = __expf(s1[j] - 16.f);
      dn[j] += p0 + p1;
      const int r = g4 * 4 + j;
      const unsigned short h0 = f2bf(p0), h1 = f2bf(p1);
      ph_[w][r][l15] = h0;      pl_[w][r][l15] = f2bf(p0 - bf2f(h0));
      ph_[w][r][16 + l15] = h1; pl_[w][r][16 + l15] = f2bf(p1 - bf2f(h1));
    }
    const bf16x8 pAh = *(const bf16x8*)&ph_[w][l15][g4 * 8];
    const bf16x8 pAl = *(const bf16x8*)&pl_[w][l15][g4 * 8];

#pragma unroll
    for (int tl = 0; tl < 5; ++tl) {
      const bf16x8 vhf = *(const bf16x8*)&vh[tl * 16 + l15][g4 * 8];
      const bf16x8 vlf = *(const bf16x8*)&vl[tl * 16 + l15][g4 * 8];
      acc[tl] = __builtin_amdgcn_mfma_f32_16x16x32_bf16(pAh, vhf, acc[tl], 0, 0, 0);
      acc[tl] = __builtin_amdgcn_mfma_f32_16x16x32_bf16(pAh, vlf, acc[tl], 0, 0, 0);
      acc[tl] = __builtin_amdgcn_mfma_f32_16x16x32_bf16(pAl, vhf, acc[tl], 0, 0, 0);
    }
  }
#pragma unroll
  for (int j = 0; j < 4; ++j) {
    dn[j] += __shfl_xor(dn[j], 1);
    dn[j] += __shfl_xor(dn[j], 2);
    dn[j] += __shfl_xor(dn[j], 4);
    dn[j] += __shfl_xor(dn[j], 8);
  }
  float* outB = xg2 + (((size_t)z * Bv + b) * Nv) * 80;
#pragma unroll
  for (int j = 0; j < 4; ++j) {
    const float r = 1.f / dn[j];
    const int n = n0 + w * 16 + g4 * 4 + j;
#pragma unroll
    for (int tl = 0; tl < 5; ++tl) {
      const int c = tl * 16 + l15;
      if (c < 67) outB[(size_t)n * 80 + c] = acc[tl][j] * r;
    }
  }
}

// ---------------------------------------------------------------------------
// K2 v2: thread = (o = tid&63, bg = tid>>6) owning 8 batches.
// gout = xt@W0[n] + xg2@W1[n] + tb ; q=LN(gout); temporal attn; gate.
// grid (Nv, 1, ngates), block 256
__global__ __launch_bounds__(256) void k_k2(const float* __restrict__ x,
                                            const float* __restrict__ Wb,
                                            const float* __restrict__ TB,
                                            const float* __restrict__ oln_g,
                                            const float* __restrict__ oln_b,
                                            const float* __restrict__ xg2,
                                            const float* __restrict__ srcst,
                                            const float* __restrict__ states,
                                            const float* __restrict__ stcur,
                                            float* __restrict__ zs,
                                            float* __restrict__ rb,
                                            float* __restrict__ hnew,
                                            int t, int g0) {
  const int zb = blockIdx.z;
  const int g = g0 + zb;
  const int n = blockIdx.x;
  __shared__ float xts[INXv][36];
  __shared__ float g2s[INXv][36];
  const int tid = threadIdx.x;

  {
    const int bq = tid >> 3, cc = tid & 7;
    const float* sp = &srcst[((size_t)bq * Nv + n) * HIDv + cc * 8];
    const float4 a = *(const float4*)sp;
    const float4 c = *(const float4*)(sp + 4);
    xts[3 + cc * 8 + 0][bq] = a.x; xts[3 + cc * 8 + 1][bq] = a.y;
    xts[3 + cc * 8 + 2][bq] = a.z; xts[3 + cc * 8 + 3][bq] = a.w;
    xts[3 + cc * 8 + 4][bq] = c.x; xts[3 + cc * 8 + 5][bq] = c.y;
    xts[3 + cc * 8 + 6][bq] = c.z; xts[3 + cc * 8 + 7][bq] = c.w;
    const float* gp = &xg2[(((size_t)zb * Bv + bq) * Nv + n) * 80 + cc * 8];
    const float4 p = *(const float4*)gp;
    const float4 r2 = *(const float4*)(gp + 4);
    g2s[3 + cc * 8 + 0][bq] = p.x;  g2s[3 + cc * 8 + 1][bq] = p.y;
    g2s[3 + cc * 8 + 2][bq] = p.z;  g2s[3 + cc * 8 + 3][bq] = p.w;
    g2s[3 + cc * 8 + 4][bq] = r2.x; g2s[3 + cc * 8 + 5][bq] = r2.y;
    g2s[3 + cc * 8 + 6][bq] = r2.z; g2s[3 + cc * 8 + 7][bq] = r2.w;
  }
  if (tid < Bv) {
    const int bq = tid;
    const float* xp = &x[(((size_t)bq * Tv + t) * Nv + n) * DINv];
    xts[0][bq] = xp[0]; xts[1][bq] = xp[1]; xts[2][bq] = xp[2];
    const float* gp = &xg2[(((size_t)zb * Bv + bq) * Nv + n) * 80 + 64];
    g2s[0][bq] = gp[0]; g2s[1][bq] = gp[1]; g2s[2][bq] = gp[2];
  }
  __syncthreads();

  const int o = tid & 63, bg = tid >> 6;
  const float* W0 = Wb + ((size_t)g * Nv + n) * WSZ + o;
  const float* W1 = W0 + INXv * HIDv;
  float acc[8] = {0, 0, 0, 0, 0, 0, 0, 0};
  for (int i = 0; i < INXv; ++i) {
    const float w0 = W0[i * HIDv];
    const float w1 = W1[i * HIDv];
    const float4 xa = *(const float4*)&xts[i][bg * 8];
    const float4 xc = *(const float4*)&xts[i][bg * 8 + 4];
    const float4 ga = *(const float4*)&g2s[i][bg * 8];
    const float4 gc = *(const float4*)&g2s[i][bg * 8 + 4];
    acc[0] += xa.x * w0 + ga.x * w1; acc[1] += xa.y * w0 + ga.y * w1;
    acc[2] += xa.z * w0 + ga.z * w1; acc[3] += xa.w * w0 + ga.w * w1;
    acc[4] += xc.x * w0 + gc.x * w1; acc[5] += xc.y * w0 + gc.y * w1;
    acc[6] += xc.z * w0 + gc.z * w1; acc[7] += xc.w * w0 + gc.w * w1;
  }
#pragma unroll
  for (int u = 0; u < 8; ++u)
    acc[u] += TB[(((size_t)g * Bv + bg * 8 + u) * Tv + t) * HIDv + o];

  // LN over o (wave = the 64 o's for this bg)
  const float gg = oln_g[g * HIDv + o], bb = oln_b[g * HIDv + o];
  float q[8];
#pragma unroll
  for (int u = 0; u < 8; ++u) {
    float s = acc[u];
    s += __shfl_xor(s, 1);  s += __shfl_xor(s, 2);  s += __shfl_xor(s, 4);
    s += __shfl_xor(s, 8);  s += __shfl_xor(s, 16); s += __shfl_xor(s, 32);
    const float mu = s * (1.f / 64.f);
    const float c = acc[u] - mu;
    float v = c * c;
    v += __shfl_xor(v, 1);  v += __shfl_xor(v, 2);  v += __shfl_xor(v, 4);
    v += __shfl_xor(v, 8);  v += __shfl_xor(v, 16); v += __shfl_xor(v, 32);
    const float rs = rsqrtf(v * (1.f / 64.f) + 1e-5f);
    q[u] = c * rs * gg + bb;
  }

  // temporal attention over k=0..t; head = o>>4 (reduce over o&15 lanes).
  // |q_h|<=8, |k_h|<=4 => |sc|<=8: exp without max is safe.
  float oa[8] = {0, 0, 0, 0, 0, 0, 0, 0};
  float den[8] = {0, 0, 0, 0, 0, 0, 0, 0};
  for (int k = 0; k <= t; ++k) {
#pragma unroll
    for (int u = 0; u < 8; ++u) {
      const float kv = states[(((size_t)k * Bv + bg * 8 + u) * Nv + n) * HIDv + o];
      float sc = q[u] * kv;
      sc += __shfl_xor(sc, 1); sc += __shfl_xor(sc, 2);
      sc += __shfl_xor(sc, 4); sc += __shfl_xor(sc, 8);
      const float p = __expf(sc * 0.25f);
      den[u] += p;
      oa[u] += p * kv;
    }
  }
  float pre[8];
#pragma unroll
  for (int u = 0; u < 8; ++u) pre[u] = acc[u] + oa[u] / den[u];

  if (g == 0) {
#pragma unroll
    for (int u = 0; u < 8; ++u) {
      const size_t off = ((size_t)(bg * 8 + u) * Nv + n) * HIDv + o;
      zs[off] = sigmoidf_(pre[u]) * stcur[off];
    }
  } else if (g == 1) {
#pragma unroll
    for (int u = 0; u < 8; ++u) {
      const size_t off = ((size_t)(bg * 8 + u) * Nv + n) * HIDv + o;
      rb[off] = sigmoidf_(pre[u]);
    }
  } else {
#pragma unroll
    for (int u = 0; u < 8; ++u) {
      const size_t off = ((size_t)(bg * 8 + u) * Nv + n) * HIDv + o;
      const float r = rb[off];
      hnew[off] = r * stcur[off] + (1.f - r) * tanhf(pre[u]);
    }
  }
}

// ---------------------------------------------------------------------------
__global__ __launch_bounds__(256) void k_pred(const float* __restrict__ states,
                                              const float* __restrict__ pw,
                                              const float* __restrict__ pb,
                                              float* __restrict__ out) {
  __shared__ float pws[OUTv * CSv * HIDv];
  __shared__ float pbs[OUTv];
  const int tid = threadIdx.x;
  for (int j = tid; j < OUTv * CSv * HIDv; j += 256) pws[j] = pw[j];
  if (tid < OUTv) pbs[tid] = pb[tid];
  __syncthreads();
  const int n = blockIdx.x * 256 + tid;
  const int b = blockIdx.y;
  const float* s0p = &states[(((size_t)(Tv - 1) * Bv + b) * Nv + n) * HIDv];
  const float* s1p = &states[(((size_t)Tv * Bv + b) * Nv + n) * HIDv];
  float4 va[16], vb[16];
#pragma unroll
  for (int j = 0; j < 16; ++j) {
    va[j] = *(const float4*)&s0p[j * 4];
    vb[j] = *(const float4*)&s1p[j * 4];
  }
#pragma unroll
  for (int oo = 0; oo < OUTv; ++oo) {
    float acc = pbs[oo];
    const float* w0 = &pws[(oo * CSv + 0) * HIDv];
    const float* w1 = &pws[(oo * CSv + 1) * HIDv];
#pragma unroll
    for (int j = 0; j < 16; ++j) {
      acc += va[j].x * w0[j * 4 + 0] + va[j].y * w0[j * 4 + 1] +
             va[j].z * w0[j * 4 + 2] + va[j].w * w0[j * 4 + 3];
      acc += vb[j].x * w1[j * 4 + 0] + vb[j].y * w1[j * 4 + 1] +
             vb[j].z * w1[j * 4 + 2] + vb[j].w * w1[j * 4 + 3];
    }
    out[((size_t)b * OUTv + oo) * Nv + n] = acc;
  }
}

// ---------------------------------------------------------------------------
extern "C" void kernel_launch(void* const* d_in, const int* in_sizes, int n_in,
                              void* d_out, int out_size, void* d_ws, size_t ws_size,
                              hipStream_t stream) {
  (void)in_sizes; (void)n_in; (void)out_size; (void)ws_size;
  const float* x        = (const float*)d_in[0];
  const float* node_emb = (const float*)d_in[1];
  const float* time_emb = (const float*)d_in[2];
  const float* wp       = (const float*)d_in[3];
  const float* bp       = (const float*)d_in[4];
  const float* gcn_g    = (const float*)d_in[5];
  const float* gcn_b    = (const float*)d_in[6];
  const float* out_g    = (const float*)d_in[7];
  const float* out_b    = (const float*)d_in[8];
  const float* pred_w   = (const float*)d_in[9];
  const float* pred_b   = (const float*)d_in[10];

  float* ws = (float*)d_ws;
  float* W    = ws;                                           // 13,172,736 f
  float* TB   = W   + (size_t)3 * Nv * WSZ;                   // 73,728 f
  float* ST   = TB  + (size_t)3 * Bv * Tv * HIDv;             // 13,631,488 f
  float* XG   = ST  + (size_t)(Tv + 1) * Bv * Nv * HIDv;      // 2,621,440 f
  float* ZS   = XG  + (size_t)2 * Bv * Nv * 80;               // 1,048,576 f
  float* RB   = ZS  + (size_t)Bv * Nv * HIDv;                 // 1,048,576 f
  unsigned short* EMBp = (unsigned short*)(RB + (size_t)Bv * Nv * HIDv);  // 18,874,368 u16
  unsigned short* Vs   = EMBp + (size_t)3 * Tv * Bv * Nv * 32;            // 2,621,440 u16

  hipMemsetAsync(ST, 0, (size_t)Bv * Nv * HIDv * sizeof(float), stream);
  k_emb<<<dim3(Nv / 128, Tv, Bv), 384, 0, stream>>>(node_emb, time_emb, gcn_g, gcn_b, EMBp);
  k_wpre<<<dim3(34, 3, 4), 256, 0, stream>>>(node_emb, wp, W);
  k_tb<<<dim3(Bv * Tv, 3), 64, 0, stream>>>(time_emb, bp, TB);

  for (int t = 0; t < Tv; ++t) {
    float* st_t  = ST + (size_t)t * Bv * Nv * HIDv;
    float* st_t1 = st_t + (size_t)Bv * Nv * HIDv;
    // phase A: g=0 (z) and g=1 (r)
    k_vprep<<<dim3(4, Bv), 256, 0, stream>>>(st_t, x, Vs, t);
    k_gatt<<<dim3(Nv / 64, Bv, 2), 256, 0, stream>>>(EMBp, Vs, XG, t, 0);
    k_k2<<<dim3(Nv, 1, 2), 256, 0, stream>>>(x, W, TB, out_g, out_b, XG,
                                             st_t, ST, st_t, ZS, RB, st_t1, t, 0);
    // phase B: g=2 (candidate) + GRU update
    k_vprep<<<dim3(4, Bv), 256, 0, stream>>>(ZS, x, Vs, t);
    k_gatt<<<dim3(Nv / 64, Bv, 1), 256, 0, stream>>>(EMBp, Vs, XG, t, 2);
    k_k2<<<dim3(Nv, 1, 1), 256, 0, stream>>>(x, W, TB, out_g, out_b, XG,
                                             ZS, ST, st_t, ZS, RB, st_t1, t, 2);
  }
  k_pred<<<dim3(Nv / 256, Bv), 256, 0, stream>>>(ST, pred_w, pred_b, (float*)d_out);
}

// Round 6
// 1569.867 us; speedup vs baseline: 1.4871x; 1.1059x over previous
//
#include <hip/hip_runtime.h>
#include <math.h>

#define Bv   32
#define Tv   12
#define Nv   512
#define DINv 3
#define DEv  16
#define HIDv 64
#define INXv 67   // DIN + HID
#define CSv  2
#define OUTv 12
#define WSZ  (2 * INXv * HIDv)   // 8576

typedef __attribute__((ext_vector_type(8))) short bf16x8;
typedef __attribute__((ext_vector_type(4))) float f32x4;

__device__ __forceinline__ float sigmoidf_(float x) { return 1.0f / (1.0f + __expf(-x)); }

__device__ __forceinline__ unsigned short f2bf(float f) {
  unsigned u = __float_as_uint(f);
  unsigned r = (u + 0x7FFFu + ((u >> 16) & 1u)) >> 16;
  return (unsigned short)r;
}
__device__ __forceinline__ float bf2f(unsigned short h) {
  return __uint_as_float(((unsigned)h) << 16);
}

// ---------------------------------------------------------------------------
// embp[g][t][b][n][0..15]=bf16 hi of LN'd emb, [16..31]=bf16 lo.
__global__ __launch_bounds__(384) void k_emb(const float* __restrict__ node_emb,
                                             const float* __restrict__ te,
                                             const float* __restrict__ lng,
                                             const float* __restrict__ lnb,
                                             unsigned short* __restrict__ embp) {
  const int t = blockIdx.y, b = blockIdx.z;
  const int g = threadIdx.x >> 7;
  const int nl = threadIdx.x & 127;
  const int n = blockIdx.x * 128 + nl;
  float v[16];
  float mu = 0.f;
#pragma unroll
  for (int d = 0; d < 16; ++d) {
    v[d] = node_emb[n * 16 + d] + te[(b * Tv + t) * 16 + d];
    mu += v[d];
  }
  mu *= 0.0625f;
  float var = 0.f;
#pragma unroll
  for (int d = 0; d < 16; ++d) { const float c = v[d] - mu; var += c * c; }
  var *= 0.0625f;
  const float rs = rsqrtf(var + 1e-12f);
  unsigned short hi[16], lo[16];
#pragma unroll
  for (int d = 0; d < 16; ++d) {
    const float e = (v[d] - mu) * rs * lng[g * 16 + d] + lnb[g * 16 + d];
    hi[d] = f2bf(e);
    lo[d] = f2bf(e - bf2f(hi[d]));
  }
  unsigned w[16];
#pragma unroll
  for (int d = 0; d < 8; ++d) {
    w[d] = (unsigned)hi[2 * d] | ((unsigned)hi[2 * d + 1] << 16);
    w[8 + d] = (unsigned)lo[2 * d] | ((unsigned)lo[2 * d + 1] << 16);
  }
  uint4* op = (uint4*)(embp + ((((size_t)g * Tv + t) * Bv + b) * Nv + n) * 32);
  op[0] = make_uint4(w[0], w[1], w[2], w[3]);
  op[1] = make_uint4(w[4], w[5], w[6], w[7]);
  op[2] = make_uint4(w[8], w[9], w[10], w[11]);
  op[3] = make_uint4(w[12], w[13], w[14], w[15]);
}

// ---------------------------------------------------------------------------
// W[g][n][k][i][o] = sum_d node_emb[n][d] * wp[g][d][k][i][o]
__global__ __launch_bounds__(256) void k_wpre(const float* __restrict__ node_emb,
                                              const float* __restrict__ wp,
                                              float* __restrict__ W) {
  const int g = blockIdx.y;
  const int j = blockIdx.x * 256 + threadIdx.x;
  const int n0 = blockIdx.z * 128;
  if (j >= WSZ) return;
  const float* wpg = wp + (size_t)g * (DEv * WSZ);
  float wr[16];
#pragma unroll
  for (int d = 0; d < 16; ++d) wr[d] = wpg[(size_t)d * WSZ + j];
  float* Wg = W + (size_t)g * Nv * WSZ;
  for (int n = n0; n < n0 + 128; ++n) {
    const float4 e0 = *(const float4*)(node_emb + n * 16);
    const float4 e1 = *(const float4*)(node_emb + n * 16 + 4);
    const float4 e2 = *(const float4*)(node_emb + n * 16 + 8);
    const float4 e3 = *(const float4*)(node_emb + n * 16 + 12);
    float s = e0.x * wr[0] + e0.y * wr[1] + e0.z * wr[2] + e0.w * wr[3]
            + e1.x * wr[4] + e1.y * wr[5] + e1.z * wr[6] + e1.w * wr[7]
            + e2.x * wr[8] + e2.y * wr[9] + e2.z * wr[10] + e2.w * wr[11]
            + e3.x * wr[12] + e3.y * wr[13] + e3.z * wr[14] + e3.w * wr[15];
    Wg[(size_t)n * WSZ + j] = s;
  }
}

// TB[g][b][t][o]
__global__ __launch_bounds__(64) void k_tb(const float* __restrict__ te,
                                           const float* __restrict__ bp,
                                           float* __restrict__ TB) {
  const int g = blockIdx.y;
  const int bt = blockIdx.x;
  const int b = bt / Tv, t = bt % Tv;
  const int o = threadIdx.x;
  float s = 0.f;
#pragma unroll
  for (int d = 0; d < DEv; ++d) s += te[(b * Tv + t) * DEv + d] * bp[(g * DEv + d) * HIDv + o];
  TB[(((size_t)g * Bv + b) * Tv + t) * HIDv + o] = s;
}

// ---------------------------------------------------------------------------
// Xs[t][b][plane][ci:3][m:512]: split-bf16 of x. grid (Tv, Bv), 256 thr.
__global__ __launch_bounds__(256) void k_xprep(const float* __restrict__ x,
                                               unsigned short* __restrict__ Xs) {
  const int t = blockIdx.x, b = blockIdx.y;
  const int tid = threadIdx.x;
  __shared__ float sl[1536];
  const float* xb = x + ((size_t)b * Tv + t) * (Nv * 3);
  for (int j = tid; j < 1536; j += 256) sl[j] = xb[j];
  __syncthreads();
  unsigned short* XB = Xs + ((size_t)t * Bv + b) * (2 * 3 * 512);
  for (int j = tid; j < 1536; j += 256) {
    const int ci = j >> 9, m = j & 511;
    const float v = sl[m * 3 + ci];
    const unsigned short h = f2bf(v);
    XB[(size_t)ci * 512 + m] = h;
    XB[(size_t)(3 + ci) * 512 + m] = f2bf(v - bf2f(h));
  }
}

// ---------------------------------------------------------------------------
// Graph attention, split-bf16 MFMA, m-split x2. Writes RAW numerator
// (c 0..66) and denominator (c=72) to xg2[z][mh][b][n][80].
// grid (Nv/64, Bv, ngates*2), block 256 = 4 waves.
__global__ __launch_bounds__(256) void k_gatt(const unsigned short* __restrict__ embp,
                                              const unsigned short* __restrict__ Vs,  // [b][plane][64][512]
                                              const unsigned short* __restrict__ Xs,  // [t][b][plane][3][512]
                                              float* __restrict__ xg2,
                                              int t, int g0) {
  const int bz = blockIdx.z, z = bz >> 1, mh = bz & 1;
  const int g = g0 + z;
  const int b = blockIdx.y;
  const int n0 = blockIdx.x * 64;
  const int tid = threadIdx.x;
  const int w = tid >> 6, lane = tid & 63;
  const int l15 = lane & 15, g4 = lane >> 4;

  __shared__ unsigned short vh[80][40];
  __shared__ unsigned short vl[80][40];
  __shared__ unsigned short ph_[4][16][40];
  __shared__ unsigned short pl_[4][16][40];

  // zero pad rows c=67..79 once (covered by first in-loop barrier)
  for (int i = tid; i < 13 * 40; i += 256) {
    vh[67 + i / 40][i % 40] = 0;
    vl[67 + i / 40][i % 40] = 0;
  }

  const unsigned short* embB = embp + ((((size_t)g * Tv + t) * Bv + b) * Nv) * 32;
  const unsigned short* VsB = Vs + (size_t)b * 128 * 512;
  const unsigned short* XsB = Xs + ((size_t)t * Bv + b) * (6 * 512);

  const int qrow = n0 + w * 16 + l15;
  const bf16x8 qhi = *(const bf16x8*)(embB + (size_t)qrow * 32 + (g4 & 1) * 8);
  const bf16x8 qlo = *(const bf16x8*)(embB + (size_t)qrow * 32 + 16 + (g4 & 1) * 8);

  f32x4 acc[5];
#pragma unroll
  for (int i = 0; i < 5; ++i) acc[i] = (f32x4){0.f, 0.f, 0.f, 0.f};
  float dn[4] = {0.f, 0.f, 0.f, 0.f};

  const int mbase = mh * 256;
  for (int m0 = mbase; m0 < mbase + 256; m0 += 32) {
    __syncthreads();
    // stage V (128 rows from Vs) + x (6 rows from Xs), 16B chunks
    for (int j = tid; j < 536; j += 256) {
      if (j < 512) {
        const int r = j >> 2, ch = j & 3;
        const int c = r & 63, plane = r >> 6;
        const uint4 v = *(const uint4*)(VsB + (size_t)r * 512 + m0 + ch * 8);
        if (plane) *(uint4*)&vl[c][ch * 8] = v;
        else       *(uint4*)&vh[c][ch * 8] = v;
      } else {
        const int j2 = j - 512;
        const int r2 = j2 >> 2, ch = j2 & 3;
        const int ci = r2 % 3, plane = r2 / 3;
        const uint4 v = *(const uint4*)(XsB + (size_t)r2 * 512 + m0 + ch * 8);
        if (plane) *(uint4*)&vl[64 + ci][ch * 8] = v;
        else       *(uint4*)&vh[64 + ci][ch * 8] = v;
      }
    }
    __syncthreads();

    // scores (exact split product via [hi|lo]-packed K)
    const bf16x8 eb0 = *(const bf16x8*)(embB + (size_t)(m0 + l15) * 32 + g4 * 8);
    const bf16x8 eb1 = *(const bf16x8*)(embB + (size_t)(m0 + 16 + l15) * 32 + g4 * 8);
    f32x4 s0 = (f32x4){0.f, 0.f, 0.f, 0.f};
    f32x4 s1 = (f32x4){0.f, 0.f, 0.f, 0.f};
    s0 = __builtin_amdgcn_mfma_f32_16x16x32_bf16(qhi, eb0, s0, 0, 0, 0);
    s0 = __builtin_amdgcn_mfma_f32_16x16x32_bf16(qlo, eb0, s0, 0, 0, 0);
    s1 = __builtin_amdgcn_mfma_f32_16x16x32_bf16(qhi, eb1, s1, 0, 0, 0);
    s1 = __builtin_amdgcn_mfma_f32_16x16x32_bf16(qlo, eb1, s1, 0, 0, 0);

    // |s|<=16 (LN'd emb, g=1,b=0): p = exp(s-16), no online max needed
#pragma unroll
    for (int j = 0; j < 4; ++j) {
      const float p0 = __expf(s0[j] - 16.f);
      const float p1 = __expf(s1[j] - 16.f);
      dn[j] += p0 + p1;
      const int r = g4 * 4 + j;
      const unsigned short h0 = f2bf(p0), h1 = f2bf(p1);
      ph_[w][r][l15] = h0;      pl_[w][r][l15] = f2bf(p0 - bf2f(h0));
      ph_[w][r][16 + l15] = h1; pl_[w][r][16 + l15] = f2bf(p1 - bf2f(h1));
    }
    const bf16x8 pAh = *(const bf16x8*)&ph_[w][l15][g4 * 8];
    const bf16x8 pAl = *(const bf16x8*)&pl_[w][l15][g4 * 8];

#pragma unroll
    for (int tl = 0; tl < 5; ++tl) {
      const bf16x8 vhf = *(const bf16x8*)&vh[tl * 16 + l15][g4 * 8];
      const bf16x8 vlf = *(const bf16x8*)&vl[tl * 16 + l15][g4 * 8];
      acc[tl] = __builtin_amdgcn_mfma_f32_16x16x32_bf16(pAh, vhf, acc[tl], 0, 0, 0);
      acc[tl] = __builtin_amdgcn_mfma_f32_16x16x32_bf16(pAh, vlf, acc[tl], 0, 0, 0);
      acc[tl] = __builtin_amdgcn_mfma_f32_16x16x32_bf16(pAl, vhf, acc[tl], 0, 0, 0);
    }
  }
#pragma unroll
  for (int j = 0; j < 4; ++j) {
    dn[j] += __shfl_xor(dn[j], 1);
    dn[j] += __shfl_xor(dn[j], 2);
    dn[j] += __shfl_xor(dn[j], 4);
    dn[j] += __shfl_xor(dn[j], 8);
  }
  float* outB = xg2 + ((((size_t)z * 2 + mh) * Bv + b) * Nv) * 80;
#pragma unroll
  for (int j = 0; j < 4; ++j) {
    const int n = n0 + w * 16 + g4 * 4 + j;
#pragma unroll
    for (int tl = 0; tl < 5; ++tl) {
      const int c = tl * 16 + l15;
      if (c < 67) outB[(size_t)n * 80 + c] = acc[tl][j];
    }
    if (l15 == 0) outB[(size_t)n * 80 + 72] = dn[j];
  }
}

// ---------------------------------------------------------------------------
// K2 (templated on #gates in block). 512 threads.
// NG==2: tid>>8 = gate (phase A, g=0,1), 4 bgroups x 8 batches.
// NG==1: single gate (phase B, g=2), 8 bgroups x 4 batches.
// Combines gatt's m-split halves; epilogue writes split-bf16 V planes
// (g==0 -> z*state into Vout; g==2 -> hnew into Vout).
template <int NG>
__global__ __launch_bounds__(512) void k_k2(const float* __restrict__ x,
                                            const float* __restrict__ Wb,
                                            const float* __restrict__ TB,
                                            const float* __restrict__ oln_g,
                                            const float* __restrict__ oln_b,
                                            const float* __restrict__ xg2,
                                            const float* __restrict__ srcst,
                                            const float* __restrict__ states,
                                            const float* __restrict__ stcur,
                                            float* __restrict__ zs,
                                            float* __restrict__ rb,
                                            float* __restrict__ hnew,
                                            unsigned short* __restrict__ Vout,
                                            int t, int g0) {
  const int n = blockIdx.x;
  const int tid = threadIdx.x;
  __shared__ float xts[INXv][36];
  __shared__ float g2s[NG][INXv][36];
  __shared__ float rden_s[NG][32];

  // pass 0: denominators + xts staging
  if (tid < NG * 32) {
    const int gz2 = tid >> 5, bq = tid & 31;
    const size_t base = ((((size_t)gz2 * 2) * Bv + bq) * Nv + n) * 80;
    const float d = xg2[base + 72] + xg2[base + (size_t)Bv * Nv * 80 + 72];
    rden_s[gz2][bq] = 1.f / d;
  }
  if (tid < 256) {
    const int bq = tid >> 3, cc = tid & 7;
    const float* sp = &srcst[((size_t)bq * Nv + n) * HIDv + cc * 8];
    const float4 a = *(const float4*)sp;
    const float4 c = *(const float4*)(sp + 4);
    xts[3 + cc * 8 + 0][bq] = a.x; xts[3 + cc * 8 + 1][bq] = a.y;
    xts[3 + cc * 8 + 2][bq] = a.z; xts[3 + cc * 8 + 3][bq] = a.w;
    xts[3 + cc * 8 + 4][bq] = c.x; xts[3 + cc * 8 + 5][bq] = c.y;
    xts[3 + cc * 8 + 6][bq] = c.z; xts[3 + cc * 8 + 7][bq] = c.w;
  }
  if (tid < Bv) {
    const float* xp = &x[(((size_t)tid * Tv + t) * Nv + n) * DINv];
    xts[0][tid] = xp[0]; xts[1][tid] = xp[1]; xts[2][tid] = xp[2];
  }
  __syncthreads();

  // pass 1: g2s = (num_h0 + num_h1) * rden
  for (int j = tid; j < NG * 256; j += 512) {
    const int gz2 = j >> 8, jj = j & 255;
    const int bq = jj >> 3, cc = jj & 7;
    const float rd = rden_s[gz2][bq];
    const float* p0 = xg2 + ((((size_t)gz2 * 2 + 0) * Bv + bq) * Nv + n) * 80 + cc * 8;
    const float* p1 = p0 + (size_t)Bv * Nv * 80;
    const float4 a0 = *(const float4*)p0;
    const float4 a1 = *(const float4*)(p0 + 4);
    const float4 c0 = *(const float4*)p1;
    const float4 c1 = *(const float4*)(p1 + 4);
    g2s[gz2][3 + cc * 8 + 0][bq] = (a0.x + c0.x) * rd;
    g2s[gz2][3 + cc * 8 + 1][bq] = (a0.y + c0.y) * rd;
    g2s[gz2][3 + cc * 8 + 2][bq] = (a0.z + c0.z) * rd;
    g2s[gz2][3 + cc * 8 + 3][bq] = (a0.w + c0.w) * rd;
    g2s[gz2][3 + cc * 8 + 4][bq] = (a1.x + c1.x) * rd;
    g2s[gz2][3 + cc * 8 + 5][bq] = (a1.y + c1.y) * rd;
    g2s[gz2][3 + cc * 8 + 6][bq] = (a1.z + c1.z) * rd;
    g2s[gz2][3 + cc * 8 + 7][bq] = (a1.w + c1.w) * rd;
  }
  for (int j = tid; j < NG * 96; j += 512) {
    const int gz2 = j / 96, jj = j % 96;
    const int bq = jj / 3, ci = jj % 3;
    const float rd = rden_s[gz2][bq];
    const size_t base = ((((size_t)gz2 * 2) * Bv + bq) * Nv + n) * 80 + 64 + ci;
    g2s[gz2][ci][bq] = (xg2[base] + xg2[base + (size_t)Bv * Nv * 80]) * rd;
  }
  __syncthreads();

  constexpr int NB = (NG == 2) ? 8 : 4;
  const int gz = (NG == 2) ? (tid >> 8) : 0;
  const int g = g0 + gz;
  const int tl_ = (NG == 2) ? (tid & 255) : tid;
  const int o = tl_ & 63;
  const int bg = (NG == 2) ? ((tl_ >> 6) & 3) : (tl_ >> 6);
  const int bb0 = bg * NB;

  const float* W0 = Wb + ((size_t)g * Nv + n) * WSZ + o;
  const float* W1 = W0 + INXv * HIDv;
  float acc[NB];
#pragma unroll
  for (int u = 0; u < NB; ++u) acc[u] = 0.f;
  for (int i = 0; i < INXv; ++i) {
    const float w0 = W0[i * HIDv];
    const float w1 = W1[i * HIDv];
#pragma unroll
    for (int u4 = 0; u4 < NB / 4; ++u4) {
      const float4 xa = *(const float4*)&xts[i][bb0 + u4 * 4];
      const float4 ga = *(const float4*)&g2s[gz][i][bb0 + u4 * 4];
      acc[u4 * 4 + 0] += xa.x * w0 + ga.x * w1;
      acc[u4 * 4 + 1] += xa.y * w0 + ga.y * w1;
      acc[u4 * 4 + 2] += xa.z * w0 + ga.z * w1;
      acc[u4 * 4 + 3] += xa.w * w0 + ga.w * w1;
    }
  }
#pragma unroll
  for (int u = 0; u < NB; ++u)
    acc[u] += TB[(((size_t)g * Bv + bb0 + u) * Tv + t) * HIDv + o];

  // LN over o (64 lanes of this wave)
  const float gg = oln_g[g * HIDv + o], bb = oln_b[g * HIDv + o];
  float q[NB];
#pragma unroll
  for (int u = 0; u < NB; ++u) {
    float s = acc[u];
    s += __shfl_xor(s, 1);  s += __shfl_xor(s, 2);  s += __shfl_xor(s, 4);
    s += __shfl_xor(s, 8);  s += __shfl_xor(s, 16); s += __shfl_xor(s, 32);
    const float mu = s * (1.f / 64.f);
    const float c = acc[u] - mu;
    float v = c * c;
    v += __shfl_xor(v, 1);  v += __shfl_xor(v, 2);  v += __shfl_xor(v, 4);
    v += __shfl_xor(v, 8);  v += __shfl_xor(v, 16); v += __shfl_xor(v, 32);
    const float rs = rsqrtf(v * (1.f / 64.f) + 1e-5f);
    q[u] = c * rs * gg + bb;
  }

  // temporal attention over k=0..t (head = o>>4; |sc|<=8 -> no max needed)
  float oa[NB], den[NB];
#pragma unroll
  for (int u = 0; u < NB; ++u) { oa[u] = 0.f; den[u] = 0.f; }
  for (int k = 0; k <= t; ++k) {
#pragma unroll
    for (int u = 0; u < NB; ++u) {
      const float kv = states[(((size_t)k * Bv + bb0 + u) * Nv + n) * HIDv + o];
      float sc = q[u] * kv;
      sc += __shfl_xor(sc, 1); sc += __shfl_xor(sc, 2);
      sc += __shfl_xor(sc, 4); sc += __shfl_xor(sc, 8);
      const float p = __expf(sc * 0.25f);
      den[u] += p;
      oa[u] += p * kv;
    }
  }
  float pre[NB];
#pragma unroll
  for (int u = 0; u < NB; ++u) pre[u] = acc[u] + oa[u] / den[u];

  if (g == 0) {
#pragma unroll
    for (int u = 0; u < NB; ++u) {
      const int bq = bb0 + u;
      const size_t off = ((size_t)bq * Nv + n) * HIDv + o;
      const float val = sigmoidf_(pre[u]) * stcur[off];
      zs[off] = val;
      const unsigned short h = f2bf(val);
      Vout[((size_t)(bq * 2 + 0) * 64 + o) * 512 + n] = h;
      Vout[((size_t)(bq * 2 + 1) * 64 + o) * 512 + n] = f2bf(val - bf2f(h));
    }
  } else if (g == 1) {
#pragma unroll
    for (int u = 0; u < NB; ++u) {
      const size_t off = ((size_t)(bb0 + u) * Nv + n) * HIDv + o;
      rb[off] = sigmoidf_(pre[u]);
    }
  } else {
#pragma unroll
    for (int u = 0; u < NB; ++u) {
      const int bq = bb0 + u;
      const size_t off = ((size_t)bq * Nv + n) * HIDv + o;
      const float r = rb[off];
      const float val = r * stcur[off] + (1.f - r) * tanhf(pre[u]);
      hnew[off] = val;
      const unsigned short h = f2bf(val);
      Vout[((size_t)(bq * 2 + 0) * 64 + o) * 512 + n] = h;
      Vout[((size_t)(bq * 2 + 1) * 64 + o) * 512 + n] = f2bf(val - bf2f(h));
    }
  }
}

// ---------------------------------------------------------------------------
__global__ __launch_bounds__(256) void k_pred(const float* __restrict__ states,
                                              const float* __restrict__ pw,
                                              const float* __restrict__ pb,
                                              float* __restrict__ out) {
  __shared__ float pws[OUTv * CSv * HIDv];
  __shared__ float pbs[OUTv];
  const int tid = threadIdx.x;
  for (int j = tid; j < OUTv * CSv * HIDv; j += 256) pws[j] = pw[j];
  if (tid < OUTv) pbs[tid] = pb[tid];
  __syncthreads();
  const int n = blockIdx.x * 256 + tid;
  const int b = blockIdx.y;
  const float* s0p = &states[(((size_t)(Tv - 1) * Bv + b) * Nv + n) * HIDv];
  const float* s1p = &states[(((size_t)Tv * Bv + b) * Nv + n) * HIDv];
  float4 va[16], vb[16];
#pragma unroll
  for (int j = 0; j < 16; ++j) {
    va[j] = *(const float4*)&s0p[j * 4];
    vb[j] = *(const float4*)&s1p[j * 4];
  }
#pragma unroll
  for (int oo = 0; oo < OUTv; ++oo) {
    float acc = pbs[oo];
    const float* w0 = &pws[(oo * CSv + 0) * HIDv];
    const float* w1 = &pws[(oo * CSv + 1) * HIDv];
#pragma unroll
    for (int j = 0; j < 16; ++j) {
      acc += va[j].x * w0[j * 4 + 0] + va[j].y * w0[j * 4 + 1] +
             va[j].z * w0[j * 4 + 2] + va[j].w * w0[j * 4 + 3];
      acc += vb[j].x * w1[j * 4 + 0] + vb[j].y * w1[j * 4 + 1] +
             vb[j].z * w1[j * 4 + 2] + vb[j].w * w1[j * 4 + 3];
    }
    out[((size_t)b * OUTv + oo) * Nv + n] = acc;
  }
}

// ---------------------------------------------------------------------------
extern "C" void kernel_launch(void* const* d_in, const int* in_sizes, int n_in,
                              void* d_out, int out_size, void* d_ws, size_t ws_size,
                              hipStream_t stream) {
  (void)in_sizes; (void)n_in; (void)out_size; (void)ws_size;
  const float* x        = (const float*)d_in[0];
  const float* node_emb = (const float*)d_in[1];
  const float* time_emb = (const float*)d_in[2];
  const float* wp       = (const float*)d_in[3];
  const float* bp       = (const float*)d_in[4];
  const float* gcn_g    = (const float*)d_in[5];
  const float* gcn_b    = (const float*)d_in[6];
  const float* out_g    = (const float*)d_in[7];
  const float* out_b    = (const float*)d_in[8];
  const float* pred_w   = (const float*)d_in[9];
  const float* pred_b   = (const float*)d_in[10];

  float* ws = (float*)d_ws;
  float* W    = ws;                                           // 13,172,736 f
  float* TB   = W   + (size_t)3 * Nv * WSZ;                   // 73,728 f
  float* ST   = TB  + (size_t)3 * Bv * Tv * HIDv;             // 13,631,488 f
  float* XG   = ST  + (size_t)(Tv + 1) * Bv * Nv * HIDv;      // [2][2][32][512][80] = 5,242,880 f
  float* ZS   = XG  + (size_t)4 * Bv * Nv * 80;               // 1,048,576 f
  float* RB   = ZS  + (size_t)Bv * Nv * HIDv;                 // 1,048,576 f
  unsigned short* EMBp = (unsigned short*)(RB + (size_t)Bv * Nv * HIDv);  // 18,874,368 u16
  unsigned short* VsA  = EMBp + (size_t)3 * Tv * Bv * Nv * 32;            // 2,097,152 u16
  unsigned short* VsB  = VsA + (size_t)Bv * 128 * 512;                    // 2,097,152 u16
  unsigned short* Xs   = VsB + (size_t)Bv * 128 * 512;                    // 1,179,648 u16

  hipMemsetAsync(ST, 0, (size_t)Bv * Nv * HIDv * sizeof(float), stream);
  hipMemsetAsync(VsA, 0, (size_t)Bv * 128 * 512 * sizeof(unsigned short), stream);
  k_emb<<<dim3(Nv / 128, Tv, Bv), 384, 0, stream>>>(node_emb, time_emb, gcn_g, gcn_b, EMBp);
  k_wpre<<<dim3(34, 3, 4), 256, 0, stream>>>(node_emb, wp, W);
  k_tb<<<dim3(Bv * Tv, 3), 64, 0, stream>>>(time_emb, bp, TB);
  k_xprep<<<dim3(Tv, Bv), 256, 0, stream>>>(x, Xs);

  for (int t = 0; t < Tv; ++t) {
    float* st_t  = ST + (size_t)t * Bv * Nv * HIDv;
    float* st_t1 = st_t + (size_t)Bv * Nv * HIDv;
    // phase A: g=0 (z) and g=1 (r); V = state (VsA)
    k_gatt<<<dim3(Nv / 64, Bv, 4), 256, 0, stream>>>(EMBp, VsA, Xs, XG, t, 0);
    k_k2<2><<<dim3(Nv), 512, 0, stream>>>(x, W, TB, out_g, out_b, XG,
                                          st_t, ST, st_t, ZS, RB, st_t1, VsB, t, 0);
    // phase B: g=2 (candidate) + GRU update; V = z*state (VsB)
    k_gatt<<<dim3(Nv / 64, Bv, 2), 256, 0, stream>>>(EMBp, VsB, Xs, XG, t, 2);
    k_k2<1><<<dim3(Nv), 512, 0, stream>>>(x, W, TB, out_g, out_b, XG,
                                          ZS, ST, st_t, ZS, RB, st_t1, VsA, t, 2);
  }
  k_pred<<<dim3(Nv / 256, Bv), 256, 0, stream>>>(ST, pred_w, pred_b, (float*)d_out);
}